// Round 1
// baseline (1539.765 us; speedup 1.0000x reference)
//
#include <hip/hip_runtime.h>

// Mamba block fwd: B=2, L=1024, D=1024, DIN=2048, N=16, R=64, K=4
#define LSEQ 1024
#define DMODEL 1024
#define DINNER 2048
#define NSTATE 16
#define RRANK 64

__device__ __forceinline__ float sigmoidf_(float x) {
    return 1.0f / (1.0f + __expf(-x));
}
__device__ __forceinline__ float softplusf_(float x) {
    return (x > 20.0f) ? x : log1pf(__expf(x));
}

// ---------------------------------------------------------------------------
// Generic fp32 GEMM: C[M,N] = A[M,K(lda)] * B[K,N].  Row-major everywhere.
// grid = (N/BN, M/BM), 256 threads, TM x TN per thread micro-tile.
// ---------------------------------------------------------------------------
template<int BM, int BN, int BK, int TM, int TN>
__global__ __launch_bounds__(256) void sgemm_kernel(
    const float* __restrict__ A, const float* __restrict__ B,
    float* __restrict__ C, int M, int N, int K, int lda)
{
    static_assert((BM / TM) * (BN / TN) == 256, "256 threads");
    __shared__ float As[BK][BM + 4];   // transposed: As[k][m], row 16B-aligned
    __shared__ float Bs[BK][BN + 4];

    const int tid  = threadIdx.x;
    const int tx   = tid % (BN / TN);
    const int ty   = tid / (BN / TN);
    const int row0 = blockIdx.y * BM;
    const int col0 = blockIdx.x * BN;

    float acc[TM][TN];
    #pragma unroll
    for (int i = 0; i < TM; ++i)
        #pragma unroll
        for (int j = 0; j < TN; ++j) acc[i][j] = 0.0f;

    for (int k0 = 0; k0 < K; k0 += BK) {
        // stage A tile (BM x BK), float4 along K, store transposed
        #pragma unroll
        for (int i = 0; i < (BM * BK) / (4 * 256); ++i) {
            int lin = tid + i * 256;
            int m  = lin / (BK / 4);
            int kq = lin % (BK / 4);
            float4 v = *(const float4*)&A[(size_t)(row0 + m) * lda + k0 + kq * 4];
            As[kq * 4 + 0][m] = v.x;
            As[kq * 4 + 1][m] = v.y;
            As[kq * 4 + 2][m] = v.z;
            As[kq * 4 + 3][m] = v.w;
        }
        // stage B tile (BK x BN), natural layout
        #pragma unroll
        for (int i = 0; i < (BK * BN) / (4 * 256); ++i) {
            int lin = tid + i * 256;
            int kk = lin / (BN / 4);
            int nq = lin % (BN / 4);
            *(float4*)&Bs[kk][nq * 4] =
                *(const float4*)&B[(size_t)(k0 + kk) * N + col0 + nq * 4];
        }
        __syncthreads();
        #pragma unroll
        for (int kk = 0; kk < BK; ++kk) {
            float a[TM], bb[TN];
            #pragma unroll
            for (int i = 0; i < TM; i += 4)
                *(float4*)&a[i] = *(const float4*)&As[kk][ty * TM + i];
            #pragma unroll
            for (int j = 0; j < TN; j += 4)
                *(float4*)&bb[j] = *(const float4*)&Bs[kk][tx * TN + j];
            #pragma unroll
            for (int i = 0; i < TM; ++i)
                #pragma unroll
                for (int j = 0; j < TN; ++j)
                    acc[i][j] = fmaf(a[i], bb[j], acc[i][j]);
        }
        __syncthreads();
    }
    #pragma unroll
    for (int i = 0; i < TM; ++i)
        #pragma unroll
        for (int j = 0; j < TN; j += 4) {
            float4 v = make_float4(acc[i][j], acc[i][j + 1], acc[i][j + 2], acc[i][j + 3]);
            *(float4*)&C[(size_t)(row0 + ty * TM + i) * N + col0 + tx * TN + j] = v;
        }
}

// ---------------------------------------------------------------------------
// Causal depthwise conv (K=4) + SiLU.  Reads x_in half of xz, writes x_conv.
// One thread per 4 channels. grid = B*L*(DIN/4)/256 blocks.
// ---------------------------------------------------------------------------
__global__ __launch_bounds__(256) void conv_silu_kernel(
    const float* __restrict__ xz, const float* __restrict__ cw,
    const float* __restrict__ cb, float* __restrict__ xconv)
{
    const int idx = blockIdx.x * 256 + threadIdx.x;   // over B*L*(DIN/4)
    const int dq  = idx % (DINNER / 4);
    const int bl  = idx / (DINNER / 4);               // b*L + l
    const int l   = bl % LSEQ;
    const int d0  = dq * 4;

    const float4* cw4 = (const float4*)cw;            // conv_w row d = 4 taps = 1 float4
    const float4 W0 = cw4[d0 + 0];
    const float4 W1 = cw4[d0 + 1];
    const float4 W2 = cw4[d0 + 2];
    const float4 W3 = cw4[d0 + 3];
    float4 s = *(const float4*)&cb[d0];

    #pragma unroll
    for (int k = 0; k < 4; ++k) {
        int ls = l + k - 3;                           // causal: x_in[l+k-3]
        if (ls >= 0) {
            float4 xv = *(const float4*)&xz[(size_t)(bl + k - 3) * (2 * DINNER) + d0];
            s.x = fmaf(xv.x, ((const float*)&W0)[k], s.x);
            s.y = fmaf(xv.y, ((const float*)&W1)[k], s.y);
            s.z = fmaf(xv.z, ((const float*)&W2)[k], s.z);
            s.w = fmaf(xv.w, ((const float*)&W3)[k], s.w);
        }
    }
    s.x *= sigmoidf_(s.x);
    s.y *= sigmoidf_(s.y);
    s.z *= sigmoidf_(s.z);
    s.w *= sigmoidf_(s.w);
    *(float4*)&xconv[(size_t)idx * 4] = s;
}

// ---------------------------------------------------------------------------
// x_proj split-K GEMM: x_dbl[2048,96] += x_conv[2048,2048] * W_x[2048,96]
// grid = (M/64, 8 k-splits); x_dbl must be pre-zeroed; atomicAdd epilogue.
// ---------------------------------------------------------------------------
__global__ __launch_bounds__(256) void xproj_splitk_kernel(
    const float* __restrict__ xc, const float* __restrict__ Wx, float* xdbl)
{
    __shared__ float As[32][64 + 4];   // transposed x_conv tile
    __shared__ float Ws[32][96 + 4];

    const int tid  = threadIdx.x;
    const int tx   = tid % 32;         // cols tx, tx+32, tx+64
    const int ty   = tid / 32;         // rows ty*8 .. ty*8+7
    const int row0 = blockIdx.x * 64;
    const int k0   = blockIdx.y * 256;

    float acc[8][3];
    #pragma unroll
    for (int i = 0; i < 8; ++i) { acc[i][0] = 0.f; acc[i][1] = 0.f; acc[i][2] = 0.f; }

    for (int kt = 0; kt < 256; kt += 32) {
        const int kb = k0 + kt;
        #pragma unroll
        for (int i = 0; i < 2; ++i) {                 // 64m x 8kq float4s
            int lin = tid + i * 256;
            int m = lin / 8, kq = lin % 8;
            float4 v = *(const float4*)&xc[(size_t)(row0 + m) * DINNER + kb + kq * 4];
            As[kq * 4 + 0][m] = v.x;
            As[kq * 4 + 1][m] = v.y;
            As[kq * 4 + 2][m] = v.z;
            As[kq * 4 + 3][m] = v.w;
        }
        #pragma unroll
        for (int i = 0; i < 3; ++i) {                 // 32k x 24q float4s
            int lin = tid + i * 256;
            int kk = lin / 24, q = lin % 24;
            *(float4*)&Ws[kk][q * 4] = *(const float4*)&Wx[(size_t)(kb + kk) * 96 + q * 4];
        }
        __syncthreads();
        #pragma unroll
        for (int kk = 0; kk < 32; ++kk) {
            float a[8];
            *(float4*)&a[0] = *(const float4*)&As[kk][ty * 8];
            *(float4*)&a[4] = *(const float4*)&As[kk][ty * 8 + 4];
            float b0 = Ws[kk][tx], b1 = Ws[kk][tx + 32], b2 = Ws[kk][tx + 64];
            #pragma unroll
            for (int i = 0; i < 8; ++i) {
                acc[i][0] = fmaf(a[i], b0, acc[i][0]);
                acc[i][1] = fmaf(a[i], b1, acc[i][1]);
                acc[i][2] = fmaf(a[i], b2, acc[i][2]);
            }
        }
        __syncthreads();
    }
    #pragma unroll
    for (int i = 0; i < 8; ++i) {
        int r = row0 + ty * 8 + i;
        atomicAdd(&xdbl[(size_t)r * 96 + tx],      acc[i][0]);
        atomicAdd(&xdbl[(size_t)r * 96 + tx + 32], acc[i][1]);
        atomicAdd(&xdbl[(size_t)r * 96 + tx + 64], acc[i][2]);
    }
}

// ---------------------------------------------------------------------------
// delta = softplus(dt[2048,64] @ W_dt[64,2048] + b_dt). K=64, single stage.
// grid = (N/64, M/64), 256 threads, 4x4 per thread.
// ---------------------------------------------------------------------------
__global__ __launch_bounds__(256) void delta_kernel(
    const float* __restrict__ xdbl, const float* __restrict__ Wdt,
    const float* __restrict__ bdt, float* __restrict__ delta)
{
    __shared__ float As[64][64 + 4];   // dt^T
    __shared__ float Ws[64][64 + 4];   // W_dt tile
    const int tid  = threadIdx.x;
    const int tx   = tid % 16;
    const int ty   = tid / 16;
    const int row0 = blockIdx.y * 64;
    const int col0 = blockIdx.x * 64;

    #pragma unroll
    for (int i = 0; i < 4; ++i) {                    // 64m x 16kq float4s (dt = cols 0..63 of x_dbl)
        int lin = tid + i * 256;
        int m = lin / 16, kq = lin % 16;
        float4 v = *(const float4*)&xdbl[(size_t)(row0 + m) * 96 + kq * 4];
        As[kq * 4 + 0][m] = v.x;
        As[kq * 4 + 1][m] = v.y;
        As[kq * 4 + 2][m] = v.z;
        As[kq * 4 + 3][m] = v.w;
    }
    #pragma unroll
    for (int i = 0; i < 4; ++i) {                    // 64k x 16q float4s
        int lin = tid + i * 256;
        int kk = lin / 16, q = lin % 16;
        *(float4*)&Ws[kk][q * 4] = *(const float4*)&Wdt[(size_t)kk * DINNER + col0 + q * 4];
    }
    __syncthreads();

    float acc[4][4];
    #pragma unroll
    for (int i = 0; i < 4; ++i)
        #pragma unroll
        for (int j = 0; j < 4; ++j) acc[i][j] = 0.0f;

    #pragma unroll
    for (int kk = 0; kk < 64; ++kk) {
        float4 a = *(const float4*)&As[kk][ty * 4];
        float4 b = *(const float4*)&Ws[kk][tx * 4];
        const float* ap = (const float*)&a;
        const float* bp = (const float*)&b;
        #pragma unroll
        for (int i = 0; i < 4; ++i)
            #pragma unroll
            for (int j = 0; j < 4; ++j)
                acc[i][j] = fmaf(ap[i], bp[j], acc[i][j]);
    }

    float4 bv = *(const float4*)&bdt[col0 + tx * 4];
    const float* bvp = (const float*)&bv;
    #pragma unroll
    for (int i = 0; i < 4; ++i) {
        float4 o;
        o.x = softplusf_(acc[i][0] + bvp[0]);
        o.y = softplusf_(acc[i][1] + bvp[1]);
        o.z = softplusf_(acc[i][2] + bvp[2]);
        o.w = softplusf_(acc[i][3] + bvp[3]);
        *(float4*)&delta[(size_t)(row0 + ty * 4 + i) * DINNER + col0 + tx * 4] = o;
    }
}

// ---------------------------------------------------------------------------
// Selective scan, fused with D-skip and silu(z) gate.
// grid = (DIN/16, B), block 256 = 16 channels x 16 states.
// Thread (c,n): h for (d = bg*16+c, n); y via width-16 shuffle reduce.
// y is written into the dead x_in half of xz (same pointer as z: NOT restrict).
// ---------------------------------------------------------------------------
__global__ __launch_bounds__(256) void scan_kernel(
    const float* __restrict__ delta, const float* __restrict__ xconv,
    const float* __restrict__ xdbl, float* xz_y,
    const float* __restrict__ A_log, const float* __restrict__ Dskip)
{
    const int n = threadIdx.x & 15;
    const int c = threadIdx.x >> 4;
    const int d = blockIdx.x * 16 + c;
    const int b = blockIdx.y;

    const float Aa = -__expf(A_log[d * NSTATE + n]);   // A = -exp(A_log)
    const float Dd = Dskip[d];
    const size_t base = (size_t)b * LSEQ;

    float h = 0.0f;
    #pragma unroll 2
    for (int l = 0; l < LSEQ; ++l) {
        const size_t row = base + l;
        float dv  = delta[row * DINNER + d];           // broadcast across 16 lanes
        float xcv = xconv[row * DINNER + d];
        float Bv  = xdbl[row * 96 + RRANK + n];
        float Cv  = xdbl[row * 96 + RRANK + NSTATE + n];
        float dA  = __expf(dv * Aa);
        h = fmaf(dA, h, dv * Bv * xcv);                // h = dA*h + delta*B*u
        float p = h * Cv;
        p += __shfl_xor(p, 8, 16);
        p += __shfl_xor(p, 4, 16);
        p += __shfl_xor(p, 2, 16);
        p += __shfl_xor(p, 1, 16);
        if (n == 0) {
            float zz = xz_y[row * (2 * DINNER) + DINNER + d];   // z
            float yv = (p + xcv * Dd) * (zz * sigmoidf_(zz));   // +skip, *silu(z)
            xz_y[row * (2 * DINNER) + d] = yv;                  // overwrite dead x_in
        }
    }
}

// ---------------------------------------------------------------------------
// Post LayerNorm over D=1024. One block per row.
// ---------------------------------------------------------------------------
__global__ __launch_bounds__(256) void ln_kernel(
    const float* __restrict__ t, const float* __restrict__ g,
    const float* __restrict__ b, float* __restrict__ out)
{
    const int row = blockIdx.x;
    const int tid = threadIdx.x;
    float4 v = *(const float4*)&t[(size_t)row * DMODEL + tid * 4];
    float s = v.x + v.y + v.z + v.w;
    float q = v.x * v.x + v.y * v.y + v.z * v.z + v.w * v.w;
    #pragma unroll
    for (int m = 1; m < 64; m <<= 1) {
        s += __shfl_xor(s, m, 64);
        q += __shfl_xor(q, m, 64);
    }
    __shared__ float ss[4], qq[4];
    if ((tid & 63) == 0) { ss[tid >> 6] = s; qq[tid >> 6] = q; }
    __syncthreads();
    float S = ss[0] + ss[1] + ss[2] + ss[3];
    float Q = qq[0] + qq[1] + qq[2] + qq[3];
    float mu  = S * (1.0f / DMODEL);
    float var = Q * (1.0f / DMODEL) - mu * mu;
    float rs  = rsqrtf(var + 1e-5f);
    float4 gv = *(const float4*)&g[tid * 4];
    float4 bv = *(const float4*)&b[tid * 4];
    float4 o;
    o.x = (v.x - mu) * rs * gv.x + bv.x;
    o.y = (v.y - mu) * rs * gv.y + bv.y;
    o.z = (v.z - mu) * rs * gv.z + bv.z;
    o.w = (v.w - mu) * rs * gv.w + bv.w;
    *(float4*)&out[(size_t)row * DMODEL + tid * 4] = o;
}

// ---------------------------------------------------------------------------
extern "C" void kernel_launch(void* const* d_in, const int* in_sizes, int n_in,
                              void* d_out, int out_size, void* d_ws, size_t ws_size,
                              hipStream_t stream) {
    const float* x      = (const float*)d_in[0];
    const float* W_in   = (const float*)d_in[1];
    const float* conv_w = (const float*)d_in[2];
    const float* conv_b = (const float*)d_in[3];
    const float* W_x    = (const float*)d_in[4];
    const float* W_dt   = (const float*)d_in[5];
    const float* b_dt   = (const float*)d_in[6];
    const float* A_log  = (const float*)d_in[7];
    const float* D_skip = (const float*)d_in[8];
    const float* W_out  = (const float*)d_in[9];
    const float* ln_g   = (const float*)d_in[10];
    const float* ln_b   = (const float*)d_in[11];
    (void)in_sizes; (void)n_in; (void)out_size; (void)ws_size;

    const int M = 2 * LSEQ;  // B*L = 2048

    float* ws    = (float*)d_ws;
    float* xz    = ws;                           //  8,388,608 floats: [x_in | z], y reuses x_in half
    float* xconv = xz    + (size_t)M * 2 * DINNER;   // 4,194,304
    float* xdbl  = xconv + (size_t)M * DINNER;       //   196,608
    float* delta = xdbl  + (size_t)M * 96;           // 4,194,304
    float* tmp   = delta + (size_t)M * DINNER;       // 2,097,152
    // total: 76,283,904 bytes

    // 1) in_proj: xz = x @ W_in   [2048,1024]x[1024,4096]
    sgemm_kernel<128, 128, 16, 8, 8>
        <<<dim3((2 * DINNER) / 128, M / 128), 256, 0, stream>>>(
            x, W_in, xz, M, 2 * DINNER, DMODEL, DMODEL);

    // 2) causal depthwise conv + silu
    conv_silu_kernel<<<(M * (DINNER / 4)) / 256, 256, 0, stream>>>(
        xz, conv_w, conv_b, xconv);

    // 3) x_proj (split-K=8 + atomics)
    hipMemsetAsync(xdbl, 0, (size_t)M * 96 * sizeof(float), stream);
    xproj_splitk_kernel<<<dim3(M / 64, 8), 256, 0, stream>>>(xconv, W_x, xdbl);

    // 4) delta = softplus(dt @ W_dt + b_dt)
    delta_kernel<<<dim3(DINNER / 64, M / 64), 256, 0, stream>>>(
        xdbl, W_dt, b_dt, delta);

    // 5) selective scan + skip + gate (y -> x_in half of xz)
    scan_kernel<<<dim3(DINNER / 16, 2), 256, 0, stream>>>(
        delta, xconv, xdbl, xz, A_log, D_skip);

    // 6) out_proj: tmp = y @ W_out   [2048,2048]x[2048,1024], y has lda=4096
    sgemm_kernel<128, 64, 16, 8, 4>
        <<<dim3(DMODEL / 64, M / 128), 256, 0, stream>>>(
            xz, W_out, tmp, M, DMODEL, DINNER, 2 * DINNER);

    // 7) LayerNorm -> d_out
    ln_kernel<<<M, 256, 0, stream>>>(tmp, ln_g, ln_b, (float*)d_out);
}

// Round 2
// 932.877 us; speedup vs baseline: 1.6506x; 1.6506x over previous
//
#include <hip/hip_runtime.h>

// Mamba block fwd: B=2, L=1024, D=1024, DIN=2048, N=16, R=64, K=4
#define LSEQ 1024
#define DMODEL 1024
#define DINNER 2048
#define NSTATE 16
#define RRANK 64
#define CHUNK 32     // timesteps per scan chunk
#define NCHUNK 32    // LSEQ / CHUNK

__device__ __forceinline__ float sigmoidf_(float x) {
    return 1.0f / (1.0f + __expf(-x));
}
__device__ __forceinline__ float softplusf_(float x) {
    return (x > 20.0f) ? x : log1pf(__expf(x));
}

// ---------------------------------------------------------------------------
// Generic fp32 GEMM: C[M,N] = A[M,K(lda)] * B[K,N].  Row-major everywhere.
// grid = (N/BN, M/BM), 256 threads, TM x TN per thread micro-tile.
// ---------------------------------------------------------------------------
template<int BM, int BN, int BK, int TM, int TN>
__global__ __launch_bounds__(256) void sgemm_kernel(
    const float* __restrict__ A, const float* __restrict__ B,
    float* __restrict__ C, int M, int N, int K, int lda)
{
    static_assert((BM / TM) * (BN / TN) == 256, "256 threads");
    __shared__ float As[BK][BM + 4];   // transposed: As[k][m]
    __shared__ float Bs[BK][BN + 4];

    const int tid  = threadIdx.x;
    const int tx   = tid % (BN / TN);
    const int ty   = tid / (BN / TN);
    const int row0 = blockIdx.y * BM;
    const int col0 = blockIdx.x * BN;

    float acc[TM][TN];
    #pragma unroll
    for (int i = 0; i < TM; ++i)
        #pragma unroll
        for (int j = 0; j < TN; ++j) acc[i][j] = 0.0f;

    for (int k0 = 0; k0 < K; k0 += BK) {
        #pragma unroll
        for (int i = 0; i < (BM * BK) / (4 * 256); ++i) {
            int lin = tid + i * 256;
            int m  = lin / (BK / 4);
            int kq = lin % (BK / 4);
            float4 v = *(const float4*)&A[(size_t)(row0 + m) * lda + k0 + kq * 4];
            As[kq * 4 + 0][m] = v.x;
            As[kq * 4 + 1][m] = v.y;
            As[kq * 4 + 2][m] = v.z;
            As[kq * 4 + 3][m] = v.w;
        }
        #pragma unroll
        for (int i = 0; i < (BK * BN) / (4 * 256); ++i) {
            int lin = tid + i * 256;
            int kk = lin / (BN / 4);
            int nq = lin % (BN / 4);
            *(float4*)&Bs[kk][nq * 4] =
                *(const float4*)&B[(size_t)(k0 + kk) * N + col0 + nq * 4];
        }
        __syncthreads();
        #pragma unroll
        for (int kk = 0; kk < BK; ++kk) {
            float a[TM], bb[TN];
            #pragma unroll
            for (int i = 0; i < TM; i += 4)
                *(float4*)&a[i] = *(const float4*)&As[kk][ty * TM + i];
            #pragma unroll
            for (int j = 0; j < TN; j += 4)
                *(float4*)&bb[j] = *(const float4*)&Bs[kk][tx * TN + j];
            #pragma unroll
            for (int i = 0; i < TM; ++i)
                #pragma unroll
                for (int j = 0; j < TN; ++j)
                    acc[i][j] = fmaf(a[i], bb[j], acc[i][j]);
        }
        __syncthreads();
    }
    #pragma unroll
    for (int i = 0; i < TM; ++i)
        #pragma unroll
        for (int j = 0; j < TN; j += 4) {
            float4 v = make_float4(acc[i][j], acc[i][j + 1], acc[i][j + 2], acc[i][j + 3]);
            *(float4*)&C[(size_t)(row0 + ty * TM + i) * N + col0 + tx * TN + j] = v;
        }
}

// ---------------------------------------------------------------------------
// Causal depthwise conv (K=4) + SiLU.
// ---------------------------------------------------------------------------
__global__ __launch_bounds__(256) void conv_silu_kernel(
    const float* __restrict__ xz, const float* __restrict__ cw,
    const float* __restrict__ cb, float* __restrict__ xconv)
{
    const int idx = blockIdx.x * 256 + threadIdx.x;   // over B*L*(DIN/4)
    const int dq  = idx % (DINNER / 4);
    const int bl  = idx / (DINNER / 4);               // b*L + l
    const int l   = bl % LSEQ;
    const int d0  = dq * 4;

    const float4* cw4 = (const float4*)cw;
    const float4 W0 = cw4[d0 + 0];
    const float4 W1 = cw4[d0 + 1];
    const float4 W2 = cw4[d0 + 2];
    const float4 W3 = cw4[d0 + 3];
    float4 s = *(const float4*)&cb[d0];

    #pragma unroll
    for (int k = 0; k < 4; ++k) {
        int ls = l + k - 3;
        if (ls >= 0) {
            float4 xv = *(const float4*)&xz[(size_t)(bl + k - 3) * (2 * DINNER) + d0];
            s.x = fmaf(xv.x, ((const float*)&W0)[k], s.x);
            s.y = fmaf(xv.y, ((const float*)&W1)[k], s.y);
            s.z = fmaf(xv.z, ((const float*)&W2)[k], s.z);
            s.w = fmaf(xv.w, ((const float*)&W3)[k], s.w);
        }
    }
    s.x *= sigmoidf_(s.x);
    s.y *= sigmoidf_(s.y);
    s.z *= sigmoidf_(s.z);
    s.w *= sigmoidf_(s.w);
    *(float4*)&xconv[(size_t)idx * 4] = s;
}

// ---------------------------------------------------------------------------
// x_proj split-K GEMM: x_dbl[2048,96] += x_conv[2048,2048] * W_x[2048,96]
// ---------------------------------------------------------------------------
__global__ __launch_bounds__(256) void xproj_splitk_kernel(
    const float* __restrict__ xc, const float* __restrict__ Wx, float* xdbl)
{
    __shared__ float As[32][64 + 4];
    __shared__ float Ws[32][96 + 4];

    const int tid  = threadIdx.x;
    const int tx   = tid % 32;
    const int ty   = tid / 32;
    const int row0 = blockIdx.x * 64;
    const int k0   = blockIdx.y * 256;

    float acc[8][3];
    #pragma unroll
    for (int i = 0; i < 8; ++i) { acc[i][0] = 0.f; acc[i][1] = 0.f; acc[i][2] = 0.f; }

    for (int kt = 0; kt < 256; kt += 32) {
        const int kb = k0 + kt;
        #pragma unroll
        for (int i = 0; i < 2; ++i) {
            int lin = tid + i * 256;
            int m = lin / 8, kq = lin % 8;
            float4 v = *(const float4*)&xc[(size_t)(row0 + m) * DINNER + kb + kq * 4];
            As[kq * 4 + 0][m] = v.x;
            As[kq * 4 + 1][m] = v.y;
            As[kq * 4 + 2][m] = v.z;
            As[kq * 4 + 3][m] = v.w;
        }
        #pragma unroll
        for (int i = 0; i < 3; ++i) {
            int lin = tid + i * 256;
            int kk = lin / 24, q = lin % 24;
            *(float4*)&Ws[kk][q * 4] = *(const float4*)&Wx[(size_t)(kb + kk) * 96 + q * 4];
        }
        __syncthreads();
        #pragma unroll
        for (int kk = 0; kk < 32; ++kk) {
            float a[8];
            *(float4*)&a[0] = *(const float4*)&As[kk][ty * 8];
            *(float4*)&a[4] = *(const float4*)&As[kk][ty * 8 + 4];
            float b0 = Ws[kk][tx], b1 = Ws[kk][tx + 32], b2 = Ws[kk][tx + 64];
            #pragma unroll
            for (int i = 0; i < 8; ++i) {
                acc[i][0] = fmaf(a[i], b0, acc[i][0]);
                acc[i][1] = fmaf(a[i], b1, acc[i][1]);
                acc[i][2] = fmaf(a[i], b2, acc[i][2]);
            }
        }
        __syncthreads();
    }
    #pragma unroll
    for (int i = 0; i < 8; ++i) {
        int r = row0 + ty * 8 + i;
        atomicAdd(&xdbl[(size_t)r * 96 + tx],      acc[i][0]);
        atomicAdd(&xdbl[(size_t)r * 96 + tx + 32], acc[i][1]);
        atomicAdd(&xdbl[(size_t)r * 96 + tx + 64], acc[i][2]);
    }
}

// ---------------------------------------------------------------------------
// delta = softplus(dt[2048,64] @ W_dt[64,2048] + b_dt). K=64, single stage.
// ---------------------------------------------------------------------------
__global__ __launch_bounds__(256) void delta_kernel(
    const float* __restrict__ xdbl, const float* __restrict__ Wdt,
    const float* __restrict__ bdt, float* __restrict__ delta)
{
    __shared__ float As[64][64 + 4];
    __shared__ float Ws[64][64 + 4];
    const int tid  = threadIdx.x;
    const int tx   = tid % 16;
    const int ty   = tid / 16;
    const int row0 = blockIdx.y * 64;
    const int col0 = blockIdx.x * 64;

    #pragma unroll
    for (int i = 0; i < 4; ++i) {
        int lin = tid + i * 256;
        int m = lin / 16, kq = lin % 16;
        float4 v = *(const float4*)&xdbl[(size_t)(row0 + m) * 96 + kq * 4];
        As[kq * 4 + 0][m] = v.x;
        As[kq * 4 + 1][m] = v.y;
        As[kq * 4 + 2][m] = v.z;
        As[kq * 4 + 3][m] = v.w;
    }
    #pragma unroll
    for (int i = 0; i < 4; ++i) {
        int lin = tid + i * 256;
        int kk = lin / 16, q = lin % 16;
        *(float4*)&Ws[kk][q * 4] = *(const float4*)&Wdt[(size_t)kk * DINNER + col0 + q * 4];
    }
    __syncthreads();

    float acc[4][4];
    #pragma unroll
    for (int i = 0; i < 4; ++i)
        #pragma unroll
        for (int j = 0; j < 4; ++j) acc[i][j] = 0.0f;

    #pragma unroll
    for (int kk = 0; kk < 64; ++kk) {
        float4 a = *(const float4*)&As[kk][ty * 4];
        float4 b = *(const float4*)&Ws[kk][tx * 4];
        const float* ap = (const float*)&a;
        const float* bp = (const float*)&b;
        #pragma unroll
        for (int i = 0; i < 4; ++i)
            #pragma unroll
            for (int j = 0; j < 4; ++j)
                acc[i][j] = fmaf(ap[i], bp[j], acc[i][j]);
    }

    float4 bv = *(const float4*)&bdt[col0 + tx * 4];
    const float* bvp = (const float*)&bv;
    #pragma unroll
    for (int i = 0; i < 4; ++i) {
        float4 o;
        o.x = softplusf_(acc[i][0] + bvp[0]);
        o.y = softplusf_(acc[i][1] + bvp[1]);
        o.z = softplusf_(acc[i][2] + bvp[2]);
        o.w = softplusf_(acc[i][3] + bvp[3]);
        *(float4*)&delta[(size_t)(row0 + ty * 4 + i) * DINNER + col0 + tx * 4] = o;
    }
}

// ---------------------------------------------------------------------------
// Chunked selective scan, 3 phases.
// Phase 1: per (b,d,n,chunk) local scan from h=0 -> P = prod(dA), hloc.
//   Buffers laid out [chunk][b][d][n] so lane-adjacent n is contiguous.
// ---------------------------------------------------------------------------
__global__ __launch_bounds__(256) void scan_part1_kernel(
    const float* __restrict__ delta, const float* __restrict__ xconv,
    const float* __restrict__ xdbl, const float* __restrict__ A_log,
    float* __restrict__ Pbuf, float* __restrict__ Hbuf)
{
    const int n  = threadIdx.x & 15;
    const int c  = threadIdx.x >> 4;
    const int d  = blockIdx.x * 16 + c;
    const int b  = blockIdx.y;
    const int ch = blockIdx.z;

    const float Aa = -__expf(A_log[d * NSTATE + n]);
    const size_t base = (size_t)b * LSEQ + (size_t)ch * CHUNK;

    float h = 0.0f, P = 1.0f;
    #pragma unroll 4
    for (int t = 0; t < CHUNK; ++t) {
        const size_t row = base + t;
        float dv  = delta[row * DINNER + d];
        float xcv = xconv[row * DINNER + d];
        float Bv  = xdbl[row * 96 + RRANK + n];
        float dA  = __expf(dv * Aa);
        h = fmaf(dA, h, dv * Bv * xcv);
        P *= dA;
    }
    const size_t idx = (((size_t)ch * 2 + b) * DINNER + d) * NSTATE + n;
    Pbuf[idx] = P;
    Hbuf[idx] = h;
}

// Phase 2: per (b,d,n) serial prefix over chunks -> chunk-start states h0.
__global__ __launch_bounds__(256) void scan_combine_kernel(
    const float* __restrict__ Pbuf, const float* __restrict__ Hbuf,
    float* __restrict__ h0buf)
{
    const int idx = blockIdx.x * 256 + threadIdx.x;   // (b*DIN+d)*N+n
    float H = 0.0f;
    #pragma unroll 8
    for (int cch = 0; cch < NCHUNK; ++cch) {
        const size_t g = (size_t)cch * (2 * DINNER * NSTATE) + idx;
        h0buf[g] = H;
        H = fmaf(Pbuf[g], H, Hbuf[g]);
    }
}

// Phase 3: re-sweep each chunk from the correct h0; y = sum_n h*C via
// width-16 shuffle reduce; fuse D-skip + silu(z) gate; y -> dead x_in half.
__global__ __launch_bounds__(256) void scan_part2_kernel(
    const float* __restrict__ delta, const float* __restrict__ xconv,
    const float* __restrict__ xdbl, const float* __restrict__ h0buf,
    float* xz_y, const float* __restrict__ A_log, const float* __restrict__ Dskip)
{
    const int n  = threadIdx.x & 15;
    const int c  = threadIdx.x >> 4;
    const int d  = blockIdx.x * 16 + c;
    const int b  = blockIdx.y;
    const int ch = blockIdx.z;

    const float Aa = -__expf(A_log[d * NSTATE + n]);
    const float Dd = Dskip[d];
    const size_t base = (size_t)b * LSEQ + (size_t)ch * CHUNK;

    float h = h0buf[(((size_t)ch * 2 + b) * DINNER + d) * NSTATE + n];
    #pragma unroll 2
    for (int t = 0; t < CHUNK; ++t) {
        const size_t row = base + t;
        float dv  = delta[row * DINNER + d];
        float xcv = xconv[row * DINNER + d];
        float Bv  = xdbl[row * 96 + RRANK + n];
        float Cv  = xdbl[row * 96 + RRANK + NSTATE + n];
        float dA  = __expf(dv * Aa);
        h = fmaf(dA, h, dv * Bv * xcv);
        float p = h * Cv;
        p += __shfl_xor(p, 8, 16);
        p += __shfl_xor(p, 4, 16);
        p += __shfl_xor(p, 2, 16);
        p += __shfl_xor(p, 1, 16);
        if (n == 0) {
            float zz = xz_y[row * (2 * DINNER) + DINNER + d];   // z
            float yv = (p + xcv * Dd) * (zz * sigmoidf_(zz));
            xz_y[row * (2 * DINNER) + d] = yv;                  // overwrite dead x_in
        }
    }
}

// ---------------------------------------------------------------------------
// Post LayerNorm over D=1024. One block per row.
// ---------------------------------------------------------------------------
__global__ __launch_bounds__(256) void ln_kernel(
    const float* __restrict__ t, const float* __restrict__ g,
    const float* __restrict__ b, float* __restrict__ out)
{
    const int row = blockIdx.x;
    const int tid = threadIdx.x;
    float4 v = *(const float4*)&t[(size_t)row * DMODEL + tid * 4];
    float s = v.x + v.y + v.z + v.w;
    float q = v.x * v.x + v.y * v.y + v.z * v.z + v.w * v.w;
    #pragma unroll
    for (int m = 1; m < 64; m <<= 1) {
        s += __shfl_xor(s, m, 64);
        q += __shfl_xor(q, m, 64);
    }
    __shared__ float ss[4], qq[4];
    if ((tid & 63) == 0) { ss[tid >> 6] = s; qq[tid >> 6] = q; }
    __syncthreads();
    float S = ss[0] + ss[1] + ss[2] + ss[3];
    float Q = qq[0] + qq[1] + qq[2] + qq[3];
    float mu  = S * (1.0f / DMODEL);
    float var = Q * (1.0f / DMODEL) - mu * mu;
    float rs  = rsqrtf(var + 1e-5f);
    float4 gv = *(const float4*)&g[tid * 4];
    float4 bv = *(const float4*)&b[tid * 4];
    float4 o;
    o.x = (v.x - mu) * rs * gv.x + bv.x;
    o.y = (v.y - mu) * rs * gv.y + bv.y;
    o.z = (v.z - mu) * rs * gv.z + bv.z;
    o.w = (v.w - mu) * rs * gv.w + bv.w;
    *(float4*)&out[(size_t)row * DMODEL + tid * 4] = o;
}

// ---------------------------------------------------------------------------
extern "C" void kernel_launch(void* const* d_in, const int* in_sizes, int n_in,
                              void* d_out, int out_size, void* d_ws, size_t ws_size,
                              hipStream_t stream) {
    const float* x      = (const float*)d_in[0];
    const float* W_in   = (const float*)d_in[1];
    const float* conv_w = (const float*)d_in[2];
    const float* conv_b = (const float*)d_in[3];
    const float* W_x    = (const float*)d_in[4];
    const float* W_dt   = (const float*)d_in[5];
    const float* b_dt   = (const float*)d_in[6];
    const float* A_log  = (const float*)d_in[7];
    const float* D_skip = (const float*)d_in[8];
    const float* W_out  = (const float*)d_in[9];
    const float* ln_g   = (const float*)d_in[10];
    const float* ln_b   = (const float*)d_in[11];
    (void)in_sizes; (void)n_in; (void)out_size; (void)ws_size;

    const int M = 2 * LSEQ;  // B*L = 2048

    float* ws    = (float*)d_ws;
    float* xz    = ws;                               // 8,388,608 floats: [x_in|z]; y reuses x_in half
    float* xconv = xz    + (size_t)M * 2 * DINNER;   // 4,194,304
    float* xdbl  = xconv + (size_t)M * DINNER;       //   196,608
    float* delta = xdbl  + (size_t)M * 96;           // 4,194,304
    float* tmp   = delta + (size_t)M * DINNER;       // 2,097,152 (= h0buf during scan: exact size match)
    float* Pbuf  = tmp   + (size_t)M * DMODEL;       // 2,097,152
    float* Hbuf  = Pbuf  + (size_t)NCHUNK * 2 * DINNER * NSTATE;  // 2,097,152
    // total: 93,061,120 bytes

    // 1) in_proj: xz = x @ W_in   [2048,1024]x[1024,4096]
    sgemm_kernel<128, 128, 16, 8, 8>
        <<<dim3((2 * DINNER) / 128, M / 128), 256, 0, stream>>>(
            x, W_in, xz, M, 2 * DINNER, DMODEL, DMODEL);

    // 2) causal depthwise conv + silu
    conv_silu_kernel<<<(M * (DINNER / 4)) / 256, 256, 0, stream>>>(
        xz, conv_w, conv_b, xconv);

    // 3) x_proj (split-K=8 + atomics)
    hipMemsetAsync(xdbl, 0, (size_t)M * 96 * sizeof(float), stream);
    xproj_splitk_kernel<<<dim3(M / 64, 8), 256, 0, stream>>>(xconv, W_x, xdbl);

    // 4) delta = softplus(dt @ W_dt + b_dt)
    delta_kernel<<<dim3(DINNER / 64, M / 64), 256, 0, stream>>>(
        xdbl, W_dt, b_dt, delta);

    // 5) chunked selective scan + skip + gate (y -> x_in half of xz)
    scan_part1_kernel<<<dim3(DINNER / 16, 2, NCHUNK), 256, 0, stream>>>(
        delta, xconv, xdbl, A_log, Pbuf, Hbuf);
    scan_combine_kernel<<<(2 * DINNER * NSTATE) / 256, 256, 0, stream>>>(
        Pbuf, Hbuf, tmp /* h0buf */);
    scan_part2_kernel<<<dim3(DINNER / 16, 2, NCHUNK), 256, 0, stream>>>(
        delta, xconv, xdbl, tmp /* h0buf */, xz, A_log, D_skip);

    // 6) out_proj: tmp = y @ W_out   [2048,2048]x[2048,1024], y has lda=4096
    sgemm_kernel<128, 64, 16, 8, 4>
        <<<dim3(DMODEL / 64, M / 128), 256, 0, stream>>>(
            xz, W_out, tmp, M, DMODEL, DINNER, 2 * DINNER);

    // 7) LayerNorm -> d_out
    ln_kernel<<<M, 256, 0, stream>>>(tmp, ln_g, ln_b, (float*)d_out);
}

// Round 4
// 404.988 us; speedup vs baseline: 3.8020x; 2.3035x over previous
//
#include <hip/hip_runtime.h>

// Mamba block fwd: B=2, L=1024, D=1024, DIN=2048, N=16, R=64, K=4
#define LSEQ 1024
#define DMODEL 1024
#define DINNER 2048
#define NSTATE 16
#define RRANK 64
#define CHUNK 32     // timesteps per scan chunk
#define NCHUNK 32    // LSEQ / CHUNK
#define KSPLIT 8     // xproj split-K factor

typedef unsigned short u16;
typedef __attribute__((ext_vector_type(8))) short bf16x8;   // 8 bf16 = 4 VGPRs
typedef __attribute__((ext_vector_type(4))) float f32x4;

__device__ __forceinline__ float sigmoidf_(float x) {
    return 1.0f / (1.0f + __expf(-x));
}
__device__ __forceinline__ float softplusf_(float x) {
    return (x > 20.0f) ? x : log1pf(__expf(x));
}
__device__ __forceinline__ short f2bf(float f) {
    union { float f; unsigned u; } v; v.f = f;
    unsigned r = v.u + 0x7FFF + ((v.u >> 16) & 1);   // RNE
    return (short)(r >> 16);
}

// ---------------------------------------------------------------------------
// fp32 -> bf16 cast, 8 elements/thread.
// ---------------------------------------------------------------------------
__global__ __launch_bounds__(256) void cast_bf16_kernel(
    const float* __restrict__ in, u16* __restrict__ out)
{
    const size_t i = ((size_t)blockIdx.x * 256 + threadIdx.x) * 8;
    float4 a = *(const float4*)&in[i];
    float4 b = *(const float4*)&in[i + 4];
    bf16x8 o;
    o[0] = f2bf(a.x); o[1] = f2bf(a.y); o[2] = f2bf(a.z); o[3] = f2bf(a.w);
    o[4] = f2bf(b.x); o[5] = f2bf(b.y); o[6] = f2bf(b.z); o[7] = f2bf(b.w);
    *(bf16x8*)&out[i] = o;
}

// ---------------------------------------------------------------------------
// Transpose + cast: in[R][C] fp32 -> out[C][R] bf16.  32x32 tiles, 256 thr.
// ---------------------------------------------------------------------------
__global__ __launch_bounds__(256) void transpose_cast_kernel(
    const float* __restrict__ in, u16* __restrict__ out, int R, int C)
{
    __shared__ float t[32][33];
    const int bx = blockIdx.x * 32;   // col base (C dim)
    const int by = blockIdx.y * 32;   // row base (R dim)
    const int tx = threadIdx.x % 32, ty = threadIdx.x / 32;
    #pragma unroll
    for (int i = 0; i < 4; ++i)
        t[ty + 8 * i][tx] = in[(size_t)(by + ty + 8 * i) * C + bx + tx];
    __syncthreads();
    #pragma unroll
    for (int i = 0; i < 4; ++i)
        out[(size_t)(bx + ty + 8 * i) * R + by + tx] = (u16)f2bf(t[tx][ty + 8 * i]);
}

// ---------------------------------------------------------------------------
// bf16 MFMA GEMM: C[M,N] = A[M,K] * Bt[N,K]^T, fp32 out.
// 128 x BN block tile, BK=32, 4 waves (2m x 2n), 16x16x32 bf16 MFMA.
// A-frag: [m=lane&15][k=quad*8+j]; B-frag: [n=lane&15][k=quad*8+j];
// C/D: row=quad*4+reg, col=lane&15 (verified layouts, m89/m91/m120).
// ---------------------------------------------------------------------------
template<int BN>
__global__ __launch_bounds__(256) void mfma_gemm_kernel(
    const u16* __restrict__ A, const u16* __restrict__ Bt,
    float* __restrict__ C, int M, int N, int K)
{
    constexpr int WNS = BN / 32;            // n-subtiles per wave
    __shared__ u16 lA[128 * 32];
    __shared__ u16 lB[BN * 32];

    const int tid  = threadIdx.x;
    const int lane = tid & 63, wave = tid >> 6;
    const int quad = lane >> 4, l16 = lane & 15;
    const int wm   = (wave >> 1) * 64;       // wave row offset
    const int wn   = (wave & 1) * (BN / 2);  // wave col offset
    const int row0 = blockIdx.y * 128;
    const int col0 = blockIdx.x * BN;

    f32x4 acc[4][WNS];
    #pragma unroll
    for (int i = 0; i < 4; ++i)
        #pragma unroll
        for (int j = 0; j < WNS; ++j)
            acc[i][j] = (f32x4){0.f, 0.f, 0.f, 0.f};

    for (int k0 = 0; k0 < K; k0 += 32) {
        // stage A tile [128][32] bf16 (16B chunks: 4 chunks/row)
        #pragma unroll
        for (int t = 0; t < 2; ++t) {
            int c = tid + t * 256;
            int r = c >> 2, kc = c & 3;
            *(bf16x8*)&lA[r * 32 + kc * 8] =
                *(const bf16x8*)&A[(size_t)(row0 + r) * K + k0 + kc * 8];
        }
        // stage B tile [BN][32] bf16
        #pragma unroll
        for (int t = 0; t < BN / 64; ++t) {
            int c = tid + t * 256;
            int r = c >> 2, kc = c & 3;
            *(bf16x8*)&lB[r * 32 + kc * 8] =
                *(const bf16x8*)&Bt[(size_t)(col0 + r) * K + k0 + kc * 8];
        }
        __syncthreads();
        bf16x8 af[4], bfr[WNS];
        #pragma unroll
        for (int i = 0; i < 4; ++i)
            af[i] = *(bf16x8*)&lA[(wm + i * 16 + l16) * 32 + quad * 8];
        #pragma unroll
        for (int j = 0; j < WNS; ++j)
            bfr[j] = *(bf16x8*)&lB[(wn + j * 16 + l16) * 32 + quad * 8];
        #pragma unroll
        for (int i = 0; i < 4; ++i)
            #pragma unroll
            for (int j = 0; j < WNS; ++j)
                acc[i][j] = __builtin_amdgcn_mfma_f32_16x16x32_bf16(
                    af[i], bfr[j], acc[i][j], 0, 0, 0);
        __syncthreads();
    }
    #pragma unroll
    for (int i = 0; i < 4; ++i)
        #pragma unroll
        for (int j = 0; j < WNS; ++j)
            #pragma unroll
            for (int r = 0; r < 4; ++r)
                C[(size_t)(row0 + wm + i * 16 + quad * 4 + r) * N
                  + col0 + wn + j * 16 + l16] = acc[i][j][r];
}

// ---------------------------------------------------------------------------
// Causal depthwise conv (K=4) + SiLU.  Reads X1[2048,2048], writes x_conv.
// ---------------------------------------------------------------------------
__global__ __launch_bounds__(256) void conv_silu_kernel(
    const float* __restrict__ X1, const float* __restrict__ cw,
    const float* __restrict__ cb, float* __restrict__ xconv)
{
    const int idx = blockIdx.x * 256 + threadIdx.x;   // over B*L*(DIN/4)
    const int dq  = idx % (DINNER / 4);
    const int bl  = idx / (DINNER / 4);               // b*L + l
    const int l   = bl % LSEQ;
    const int d0  = dq * 4;

    const float4* cw4 = (const float4*)cw;
    const float4 W0 = cw4[d0 + 0];
    const float4 W1 = cw4[d0 + 1];
    const float4 W2 = cw4[d0 + 2];
    const float4 W3 = cw4[d0 + 3];
    float4 s = *(const float4*)&cb[d0];

    #pragma unroll
    for (int k = 0; k < 4; ++k) {
        int ls = l + k - 3;
        if (ls >= 0) {
            float4 xv = *(const float4*)&X1[(size_t)(bl + k - 3) * DINNER + d0];
            s.x = fmaf(xv.x, ((const float*)&W0)[k], s.x);
            s.y = fmaf(xv.y, ((const float*)&W1)[k], s.y);
            s.z = fmaf(xv.z, ((const float*)&W2)[k], s.z);
            s.w = fmaf(xv.w, ((const float*)&W3)[k], s.w);
        }
    }
    s.x *= sigmoidf_(s.x);
    s.y *= sigmoidf_(s.y);
    s.z *= sigmoidf_(s.z);
    s.w *= sigmoidf_(s.w);
    *(float4*)&xconv[(size_t)idx * 4] = s;
}

// ---------------------------------------------------------------------------
// x_proj split-K, DETERMINISTIC: each k-split writes its own partial.
// part[s][2048][96], s = blockIdx.y in [0,8). No atomics, no memset.
// ---------------------------------------------------------------------------
__global__ __launch_bounds__(256) void xproj_part_kernel(
    const float* __restrict__ xc, const float* __restrict__ Wx,
    float* __restrict__ part)
{
    __shared__ float As[32][64 + 4];
    __shared__ float Ws[32][96 + 4];

    const int tid  = threadIdx.x;
    const int tx   = tid % 32;
    const int ty   = tid / 32;
    const int row0 = blockIdx.x * 64;
    const int k0   = blockIdx.y * (DINNER / KSPLIT);

    float acc[8][3];
    #pragma unroll
    for (int i = 0; i < 8; ++i) { acc[i][0] = 0.f; acc[i][1] = 0.f; acc[i][2] = 0.f; }

    for (int kt = 0; kt < DINNER / KSPLIT; kt += 32) {
        const int kb = k0 + kt;
        #pragma unroll
        for (int i = 0; i < 2; ++i) {
            int lin = tid + i * 256;
            int m = lin / 8, kq = lin % 8;
            float4 v = *(const float4*)&xc[(size_t)(row0 + m) * DINNER + kb + kq * 4];
            As[kq * 4 + 0][m] = v.x;
            As[kq * 4 + 1][m] = v.y;
            As[kq * 4 + 2][m] = v.z;
            As[kq * 4 + 3][m] = v.w;
        }
        #pragma unroll
        for (int i = 0; i < 3; ++i) {
            int lin = tid + i * 256;
            int kk = lin / 24, q = lin % 24;
            *(float4*)&Ws[kk][q * 4] = *(const float4*)&Wx[(size_t)(kb + kk) * 96 + q * 4];
        }
        __syncthreads();
        #pragma unroll 8
        for (int kk = 0; kk < 32; ++kk) {
            float a[8];
            *(float4*)&a[0] = *(const float4*)&As[kk][ty * 8];
            *(float4*)&a[4] = *(const float4*)&As[kk][ty * 8 + 4];
            float b0 = Ws[kk][tx], b1 = Ws[kk][tx + 32], b2 = Ws[kk][tx + 64];
            #pragma unroll
            for (int i = 0; i < 8; ++i) {
                acc[i][0] = fmaf(a[i], b0, acc[i][0]);
                acc[i][1] = fmaf(a[i], b1, acc[i][1]);
                acc[i][2] = fmaf(a[i], b2, acc[i][2]);
            }
        }
        __syncthreads();
    }
    float* po = part + (size_t)blockIdx.y * (2 * LSEQ * 96);
    #pragma unroll
    for (int i = 0; i < 8; ++i) {
        int r = row0 + ty * 8 + i;
        po[(size_t)r * 96 + tx]      = acc[i][0];
        po[(size_t)r * 96 + tx + 32] = acc[i][1];
        po[(size_t)r * 96 + tx + 64] = acc[i][2];
    }
}

// Reduce the 8 partials -> xdbl[2048*96].
__global__ __launch_bounds__(256) void xproj_reduce_kernel(
    const float* __restrict__ part, float* __restrict__ xdbl)
{
    const int idx = blockIdx.x * 256 + threadIdx.x;   // [0, 2048*96)
    float s = 0.0f;
    #pragma unroll
    for (int k = 0; k < KSPLIT; ++k)
        s += part[(size_t)k * (2 * LSEQ * 96) + idx];
    xdbl[idx] = s;
}

// ---------------------------------------------------------------------------
// delta = softplus(dt[2048,64] @ W_dt[64,2048] + b_dt). K=64, single stage.
// kk loop unroll CAPPED at 8: full unroll spilled (VGPR=256, 8x write ampl).
// ---------------------------------------------------------------------------
__global__ __launch_bounds__(256) void delta_kernel(
    const float* __restrict__ xdbl, const float* __restrict__ Wdt,
    const float* __restrict__ bdt, float* __restrict__ delta)
{
    __shared__ float As[64][64 + 4];
    __shared__ float Ws[64][64 + 4];
    const int tid  = threadIdx.x;
    const int tx   = tid % 16;
    const int ty   = tid / 16;
    const int row0 = blockIdx.y * 64;
    const int col0 = blockIdx.x * 64;

    #pragma unroll
    for (int i = 0; i < 4; ++i) {
        int lin = tid + i * 256;
        int m = lin / 16, kq = lin % 16;
        float4 v = *(const float4*)&xdbl[(size_t)(row0 + m) * 96 + kq * 4];
        As[kq * 4 + 0][m] = v.x;
        As[kq * 4 + 1][m] = v.y;
        As[kq * 4 + 2][m] = v.z;
        As[kq * 4 + 3][m] = v.w;
    }
    #pragma unroll
    for (int i = 0; i < 4; ++i) {
        int lin = tid + i * 256;
        int kk = lin / 16, q = lin % 16;
        *(float4*)&Ws[kk][q * 4] = *(const float4*)&Wdt[(size_t)kk * DINNER + col0 + q * 4];
    }
    __syncthreads();

    float acc[4][4];
    #pragma unroll
    for (int i = 0; i < 4; ++i)
        #pragma unroll
        for (int j = 0; j < 4; ++j) acc[i][j] = 0.0f;

    #pragma unroll 8
    for (int kk = 0; kk < 64; ++kk) {
        float4 a = *(const float4*)&As[kk][ty * 4];
        float4 b = *(const float4*)&Ws[kk][tx * 4];
        const float* ap = (const float*)&a;
        const float* bp = (const float*)&b;
        #pragma unroll
        for (int i = 0; i < 4; ++i)
            #pragma unroll
            for (int j = 0; j < 4; ++j)
                acc[i][j] = fmaf(ap[i], bp[j], acc[i][j]);
    }

    float4 bv = *(const float4*)&bdt[col0 + tx * 4];
    const float* bvp = (const float*)&bv;
    #pragma unroll
    for (int i = 0; i < 4; ++i) {
        float4 o;
        o.x = softplusf_(acc[i][0] + bvp[0]);
        o.y = softplusf_(acc[i][1] + bvp[1]);
        o.z = softplusf_(acc[i][2] + bvp[2]);
        o.w = softplusf_(acc[i][3] + bvp[3]);
        *(float4*)&delta[(size_t)(row0 + ty * 4 + i) * DINNER + col0 + tx * 4] = o;
    }
}

// ---------------------------------------------------------------------------
// Chunked selective scan, 3 phases.
// ---------------------------------------------------------------------------
__global__ __launch_bounds__(256) void scan_part1_kernel(
    const float* __restrict__ delta, const float* __restrict__ xconv,
    const float* __restrict__ xdbl, const float* __restrict__ A_log,
    float* __restrict__ Pbuf, float* __restrict__ Hbuf)
{
    const int n  = threadIdx.x & 15;
    const int c  = threadIdx.x >> 4;
    const int d  = blockIdx.x * 16 + c;
    const int b  = blockIdx.y;
    const int ch = blockIdx.z;

    const float Aa = -__expf(A_log[d * NSTATE + n]);
    const size_t base = (size_t)b * LSEQ + (size_t)ch * CHUNK;

    float h = 0.0f, P = 1.0f;
    #pragma unroll 4
    for (int t = 0; t < CHUNK; ++t) {
        const size_t row = base + t;
        float dv  = delta[row * DINNER + d];
        float xcv = xconv[row * DINNER + d];
        float Bv  = xdbl[row * 96 + RRANK + n];
        float dA  = __expf(dv * Aa);
        h = fmaf(dA, h, dv * Bv * xcv);
        P *= dA;
    }
    const size_t idx = (((size_t)ch * 2 + b) * DINNER + d) * NSTATE + n;
    Pbuf[idx] = P;
    Hbuf[idx] = h;
}

__global__ __launch_bounds__(256) void scan_combine_kernel(
    const float* __restrict__ Pbuf, const float* __restrict__ Hbuf,
    float* __restrict__ h0buf)
{
    const int idx = blockIdx.x * 256 + threadIdx.x;   // (b*DIN+d)*N+n
    float H = 0.0f;
    #pragma unroll 8
    for (int cch = 0; cch < NCHUNK; ++cch) {
        const size_t g = (size_t)cch * (2 * DINNER * NSTATE) + idx;
        h0buf[g] = H;
        H = fmaf(Pbuf[g], H, Hbuf[g]);
    }
}

// Phase 3: resweep from h0; y = sum_n h*C (width-16 shuffle), +D-skip,
// *silu(z); emit y as bf16 (out_proj consumes bf16).
__global__ __launch_bounds__(256) void scan_part2_kernel(
    const float* __restrict__ delta, const float* __restrict__ xconv,
    const float* __restrict__ xdbl, const float* __restrict__ h0buf,
    const float* __restrict__ Z, u16* __restrict__ yb,
    const float* __restrict__ A_log, const float* __restrict__ Dskip)
{
    const int n  = threadIdx.x & 15;
    const int c  = threadIdx.x >> 4;
    const int d  = blockIdx.x * 16 + c;
    const int b  = blockIdx.y;
    const int ch = blockIdx.z;

    const float Aa = -__expf(A_log[d * NSTATE + n]);
    const float Dd = Dskip[d];
    const size_t base = (size_t)b * LSEQ + (size_t)ch * CHUNK;

    float h = h0buf[(((size_t)ch * 2 + b) * DINNER + d) * NSTATE + n];
    #pragma unroll 2
    for (int t = 0; t < CHUNK; ++t) {
        const size_t row = base + t;
        float dv  = delta[row * DINNER + d];
        float xcv = xconv[row * DINNER + d];
        float Bv  = xdbl[row * 96 + RRANK + n];
        float Cv  = xdbl[row * 96 + RRANK + NSTATE + n];
        float dA  = __expf(dv * Aa);
        h = fmaf(dA, h, dv * Bv * xcv);
        float p = h * Cv;
        p += __shfl_xor(p, 8, 16);
        p += __shfl_xor(p, 4, 16);
        p += __shfl_xor(p, 2, 16);
        p += __shfl_xor(p, 1, 16);
        if (n == 0) {
            float zz = Z[row * DINNER + d];
            float yv = (p + xcv * Dd) * (zz * sigmoidf_(zz));
            yb[row * DINNER + d] = (u16)f2bf(yv);
        }
    }
}

// ---------------------------------------------------------------------------
// Post LayerNorm over D=1024. One block per row.
// ---------------------------------------------------------------------------
__global__ __launch_bounds__(256) void ln_kernel(
    const float* __restrict__ t, const float* __restrict__ g,
    const float* __restrict__ b, float* __restrict__ out)
{
    const int row = blockIdx.x;
    const int tid = threadIdx.x;
    float4 v = *(const float4*)&t[(size_t)row * DMODEL + tid * 4];
    float s = v.x + v.y + v.z + v.w;
    float q = v.x * v.x + v.y * v.y + v.z * v.z + v.w * v.w;
    #pragma unroll
    for (int m = 1; m < 64; m <<= 1) {
        s += __shfl_xor(s, m, 64);
        q += __shfl_xor(q, m, 64);
    }
    __shared__ float ss[4], qq[4];
    if ((tid & 63) == 0) { ss[tid >> 6] = s; qq[tid >> 6] = q; }
    __syncthreads();
    float S = ss[0] + ss[1] + ss[2] + ss[3];
    float Q = qq[0] + qq[1] + qq[2] + qq[3];
    float mu  = S * (1.0f / DMODEL);
    float var = Q * (1.0f / DMODEL) - mu * mu;
    float rs  = rsqrtf(var + 1e-5f);
    float4 gv = *(const float4*)&g[tid * 4];
    float4 bv = *(const float4*)&b[tid * 4];
    float4 o;
    o.x = (v.x - mu) * rs * gv.x + bv.x;
    o.y = (v.y - mu) * rs * gv.y + bv.y;
    o.z = (v.z - mu) * rs * gv.z + bv.z;
    o.w = (v.w - mu) * rs * gv.w + bv.w;
    *(float4*)&out[(size_t)row * DMODEL + tid * 4] = o;
}

// ---------------------------------------------------------------------------
extern "C" void kernel_launch(void* const* d_in, const int* in_sizes, int n_in,
                              void* d_out, int out_size, void* d_ws, size_t ws_size,
                              hipStream_t stream) {
    const float* x      = (const float*)d_in[0];
    const float* W_in   = (const float*)d_in[1];
    const float* conv_w = (const float*)d_in[2];
    const float* conv_b = (const float*)d_in[3];
    const float* W_x    = (const float*)d_in[4];
    const float* W_dt   = (const float*)d_in[5];
    const float* b_dt   = (const float*)d_in[6];
    const float* A_log  = (const float*)d_in[7];
    const float* D_skip = (const float*)d_in[8];
    const float* W_out  = (const float*)d_in[9];
    const float* ln_g   = (const float*)d_in[10];
    const float* ln_b   = (const float*)d_in[11];
    (void)in_sizes; (void)n_in; (void)out_size; (void)ws_size;

    const int M = 2 * LSEQ;  // B*L = 2048

    // Workspace layout (floats). Total = 23,265,280 f = 93,061,120 B
    // (identical footprint to round 2, which passed replay validation).
    float* ws    = (float*)d_ws;
    float* X1    = ws;                               // 4,194,304  x_in (dead after conv)
    float* Z     = X1    + (size_t)M * DINNER;       // 4,194,304  z
    float* xconv = Z     + (size_t)M * DINNER;       // 4,194,304
    float* xdbl  = xconv + (size_t)M * DINNER;       //   196,608
    float* delta = xdbl  + (size_t)M * 96;           // 4,194,304
    float* tmp   = delta + (size_t)M * DINNER;       // 2,097,152  xproj partials -> h0 -> out_proj out
    u16*   xb    = (u16*)(tmp + (size_t)M * DMODEL); // 2,097,152 u16  x bf16
    u16*   Wbin  = xb    + (size_t)M * DMODEL;       // 4,194,304 u16  W_in^T bf16 (dead after in_proj)
    u16*   Wbout = Wbin  + (size_t)2 * DINNER * DMODEL; // 2,097,152 u16  W_out^T bf16
    // Liveness-disjoint aliases (each region has exactly one producer->consumer):
    u16*   yb    = (u16*)X1;                          // X1[0:8MB)  — y bf16 (after X1 dead)
    float* Pbuf  = X1 + (size_t)NCHUNK * 2 * DINNER * NSTATE / 2 * 2; // placeholder; set below
    Pbuf         = X1 + (size_t)2 * 1024 * 1024;      // X1[8:16MB) — 2,097,152 f
    float* Hbuf  = (float*)Wbin;                      // Wbin region (dead) — 2,097,152 f
    float* part  = tmp;                               // 8 * 2048 * 96 = 1,572,864 f <= tmp
    float* h0    = tmp;                               // after partials dead

    // 0) casts: x -> bf16; W_in -> W_in^T bf16 [4096,1024]; W_out -> W_out^T bf16 [1024,2048]
    cast_bf16_kernel<<<(M * DMODEL) / (256 * 8), 256, 0, stream>>>(x, xb);
    transpose_cast_kernel<<<dim3((2 * DINNER) / 32, DMODEL / 32), 256, 0, stream>>>(
        W_in, Wbin, DMODEL, 2 * DINNER);
    transpose_cast_kernel<<<dim3(DMODEL / 32, DINNER / 32), 256, 0, stream>>>(
        W_out, Wbout, DINNER, DMODEL);

    // 1) in_proj via bf16 MFMA: X1 = xb @ W_in[:, :2048],  Z = xb @ W_in[:, 2048:]
    mfma_gemm_kernel<128><<<dim3(DINNER / 128, M / 128), 256, 0, stream>>>(
        xb, Wbin, X1, M, DINNER, DMODEL);
    mfma_gemm_kernel<128><<<dim3(DINNER / 128, M / 128), 256, 0, stream>>>(
        xb, Wbin + (size_t)DINNER * DMODEL, Z, M, DINNER, DMODEL);

    // 2) causal depthwise conv + silu   [X1 dead after this]
    conv_silu_kernel<<<(M * (DINNER / 4)) / 256, 256, 0, stream>>>(
        X1, conv_w, conv_b, xconv);

    // 3) x_proj, deterministic split-K: partials -> reduce (no atomics/memset)
    xproj_part_kernel<<<dim3(M / 64, KSPLIT), 256, 0, stream>>>(xconv, W_x, part);
    xproj_reduce_kernel<<<(M * 96) / 256, 256, 0, stream>>>(part, xdbl);

    // 4) delta = softplus(dt @ W_dt + b_dt)
    delta_kernel<<<dim3(DINNER / 64, M / 64), 256, 0, stream>>>(
        xdbl, W_dt, b_dt, delta);

    // 5) chunked selective scan: P -> X1[8:16MB), H -> Wbin(dead), h0 -> tmp, y -> X1[0:8MB)
    scan_part1_kernel<<<dim3(DINNER / 16, 2, NCHUNK), 256, 0, stream>>>(
        delta, xconv, xdbl, A_log, Pbuf, Hbuf);
    scan_combine_kernel<<<(2 * DINNER * NSTATE) / 256, 256, 0, stream>>>(
        Pbuf, Hbuf, h0);
    scan_part2_kernel<<<dim3(DINNER / 16, 2, NCHUNK), 256, 0, stream>>>(
        delta, xconv, xdbl, h0, Z, yb, A_log, D_skip);

    // 6) out_proj via bf16 MFMA: tmp = yb @ W_out   [2048,2048]x[2048,1024]
    mfma_gemm_kernel<64><<<dim3(DMODEL / 64, M / 128), 256, 0, stream>>>(
        yb, Wbout, tmp, M, DMODEL, DINNER);

    // 7) LayerNorm -> d_out
    ln_kernel<<<M, 256, 0, stream>>>(tmp, ln_g, ln_b, (float*)d_out);
}

// Round 5
// 323.217 us; speedup vs baseline: 4.7639x; 1.2530x over previous
//
#include <hip/hip_runtime.h>

// Mamba block fwd: B=2, L=1024, D=1024, DIN=2048, N=16, R=64, K=4
#define LSEQ 1024
#define DMODEL 1024
#define DINNER 2048
#define NSTATE 16
#define RRANK 64
#define CHUNK 32     // timesteps per scan chunk
#define NCHUNK 32    // LSEQ / CHUNK
#define KSPLIT 8     // xproj split-K factor

typedef unsigned short u16;
typedef __attribute__((ext_vector_type(8))) short bf16x8;   // 8 bf16 = 4 VGPRs
typedef __attribute__((ext_vector_type(4))) float f32x4;

__device__ __forceinline__ float sigmoidf_(float x) {
    return 1.0f / (1.0f + __expf(-x));
}
__device__ __forceinline__ float softplusf_(float x) {
    return (x > 20.0f) ? x : log1pf(__expf(x));
}
__device__ __forceinline__ short f2bf(float f) {
    union { float f; unsigned u; } v; v.f = f;
    unsigned r = v.u + 0x7FFF + ((v.u >> 16) & 1);   // RNE
    return (short)(r >> 16);
}

// ---------------------------------------------------------------------------
// fp32 -> bf16 cast, 8 elements/thread.
// ---------------------------------------------------------------------------
__global__ __launch_bounds__(256) void cast_bf16_kernel(
    const float* __restrict__ in, u16* __restrict__ out)
{
    const size_t i = ((size_t)blockIdx.x * 256 + threadIdx.x) * 8;
    float4 a = *(const float4*)&in[i];
    float4 b = *(const float4*)&in[i + 4];
    bf16x8 o;
    o[0] = f2bf(a.x); o[1] = f2bf(a.y); o[2] = f2bf(a.z); o[3] = f2bf(a.w);
    o[4] = f2bf(b.x); o[5] = f2bf(b.y); o[6] = f2bf(b.z); o[7] = f2bf(b.w);
    *(bf16x8*)&out[i] = o;
}

// ---------------------------------------------------------------------------
// Transpose + cast: in[R][C] fp32 -> out[C][R] bf16.  32x32 tiles, 256 thr.
// ---------------------------------------------------------------------------
__global__ __launch_bounds__(256) void transpose_cast_kernel(
    const float* __restrict__ in, u16* __restrict__ out, int R, int C)
{
    __shared__ float t[32][33];
    const int bx = blockIdx.x * 32;   // col base (C dim)
    const int by = blockIdx.y * 32;   // row base (R dim)
    const int tx = threadIdx.x % 32, ty = threadIdx.x / 32;
    #pragma unroll
    for (int i = 0; i < 4; ++i)
        t[ty + 8 * i][tx] = in[(size_t)(by + ty + 8 * i) * C + bx + tx];
    __syncthreads();
    #pragma unroll
    for (int i = 0; i < 4; ++i)
        out[(size_t)(bx + ty + 8 * i) * R + by + tx] = (u16)f2bf(t[tx][ty + 8 * i]);
}

// ---------------------------------------------------------------------------
// bf16 MFMA GEMM: C[M,N] = A[M,K] * Bt[N,K]^T, fp32 out.
// 128 x BN block tile, BK=32, 4 waves (2m x 2n), 16x16x32 bf16 MFMA.
// ---------------------------------------------------------------------------
template<int BN>
__global__ __launch_bounds__(256) void mfma_gemm_kernel(
    const u16* __restrict__ A, const u16* __restrict__ Bt,
    float* __restrict__ C, int M, int N, int K)
{
    constexpr int WNS = BN / 32;            // n-subtiles per wave
    __shared__ u16 lA[128 * 32];
    __shared__ u16 lB[BN * 32];

    const int tid  = threadIdx.x;
    const int lane = tid & 63, wave = tid >> 6;
    const int quad = lane >> 4, l16 = lane & 15;
    const int wm   = (wave >> 1) * 64;       // wave row offset
    const int wn   = (wave & 1) * (BN / 2);  // wave col offset
    const int row0 = blockIdx.y * 128;
    const int col0 = blockIdx.x * BN;

    f32x4 acc[4][WNS];
    #pragma unroll
    for (int i = 0; i < 4; ++i)
        #pragma unroll
        for (int j = 0; j < WNS; ++j)
            acc[i][j] = (f32x4){0.f, 0.f, 0.f, 0.f};

    for (int k0 = 0; k0 < K; k0 += 32) {
        #pragma unroll
        for (int t = 0; t < 2; ++t) {
            int c = tid + t * 256;
            int r = c >> 2, kc = c & 3;
            *(bf16x8*)&lA[r * 32 + kc * 8] =
                *(const bf16x8*)&A[(size_t)(row0 + r) * K + k0 + kc * 8];
        }
        #pragma unroll
        for (int t = 0; t < BN / 64; ++t) {
            int c = tid + t * 256;
            int r = c >> 2, kc = c & 3;
            *(bf16x8*)&lB[r * 32 + kc * 8] =
                *(const bf16x8*)&Bt[(size_t)(col0 + r) * K + k0 + kc * 8];
        }
        __syncthreads();
        bf16x8 af[4], bfr[WNS];
        #pragma unroll
        for (int i = 0; i < 4; ++i)
            af[i] = *(bf16x8*)&lA[(wm + i * 16 + l16) * 32 + quad * 8];
        #pragma unroll
        for (int j = 0; j < WNS; ++j)
            bfr[j] = *(bf16x8*)&lB[(wn + j * 16 + l16) * 32 + quad * 8];
        #pragma unroll
        for (int i = 0; i < 4; ++i)
            #pragma unroll
            for (int j = 0; j < WNS; ++j)
                acc[i][j] = __builtin_amdgcn_mfma_f32_16x16x32_bf16(
                    af[i], bfr[j], acc[i][j], 0, 0, 0);
        __syncthreads();
    }
    #pragma unroll
    for (int i = 0; i < 4; ++i)
        #pragma unroll
        for (int j = 0; j < WNS; ++j)
            #pragma unroll
            for (int r = 0; r < 4; ++r)
                C[(size_t)(row0 + wm + i * 16 + quad * 4 + r) * N
                  + col0 + wn + j * 16 + l16] = acc[i][j][r];
}

// ---------------------------------------------------------------------------
// Causal depthwise conv (K=4) + SiLU.  Reads X1[2048,2048], writes x_conv.
// ---------------------------------------------------------------------------
__global__ __launch_bounds__(256) void conv_silu_kernel(
    const float* __restrict__ X1, const float* __restrict__ cw,
    const float* __restrict__ cb, float* __restrict__ xconv)
{
    const int idx = blockIdx.x * 256 + threadIdx.x;   // over B*L*(DIN/4)
    const int dq  = idx % (DINNER / 4);
    const int bl  = idx / (DINNER / 4);               // b*L + l
    const int l   = bl % LSEQ;
    const int d0  = dq * 4;

    const float4* cw4 = (const float4*)cw;
    const float4 W0 = cw4[d0 + 0];
    const float4 W1 = cw4[d0 + 1];
    const float4 W2 = cw4[d0 + 2];
    const float4 W3 = cw4[d0 + 3];
    float4 s = *(const float4*)&cb[d0];

    #pragma unroll
    for (int k = 0; k < 4; ++k) {
        int ls = l + k - 3;
        if (ls >= 0) {
            float4 xv = *(const float4*)&X1[(size_t)(bl + k - 3) * DINNER + d0];
            s.x = fmaf(xv.x, ((const float*)&W0)[k], s.x);
            s.y = fmaf(xv.y, ((const float*)&W1)[k], s.y);
            s.z = fmaf(xv.z, ((const float*)&W2)[k], s.z);
            s.w = fmaf(xv.w, ((const float*)&W3)[k], s.w);
        }
    }
    s.x *= sigmoidf_(s.x);
    s.y *= sigmoidf_(s.y);
    s.z *= sigmoidf_(s.z);
    s.w *= sigmoidf_(s.w);
    *(float4*)&xconv[(size_t)idx * 4] = s;
}

// ---------------------------------------------------------------------------
// x_proj split-K, deterministic: each k-split writes its own partial.
// ---------------------------------------------------------------------------
__global__ __launch_bounds__(256) void xproj_part_kernel(
    const float* __restrict__ xc, const float* __restrict__ Wx,
    float* __restrict__ part)
{
    __shared__ float As[32][64 + 4];
    __shared__ float Ws[32][96 + 4];

    const int tid  = threadIdx.x;
    const int tx   = tid % 32;
    const int ty   = tid / 32;
    const int row0 = blockIdx.x * 64;
    const int k0   = blockIdx.y * (DINNER / KSPLIT);

    float acc[8][3];
    #pragma unroll
    for (int i = 0; i < 8; ++i) { acc[i][0] = 0.f; acc[i][1] = 0.f; acc[i][2] = 0.f; }

    for (int kt = 0; kt < DINNER / KSPLIT; kt += 32) {
        const int kb = k0 + kt;
        #pragma unroll
        for (int i = 0; i < 2; ++i) {
            int lin = tid + i * 256;
            int m = lin / 8, kq = lin % 8;
            float4 v = *(const float4*)&xc[(size_t)(row0 + m) * DINNER + kb + kq * 4];
            As[kq * 4 + 0][m] = v.x;
            As[kq * 4 + 1][m] = v.y;
            As[kq * 4 + 2][m] = v.z;
            As[kq * 4 + 3][m] = v.w;
        }
        #pragma unroll
        for (int i = 0; i < 3; ++i) {
            int lin = tid + i * 256;
            int kk = lin / 24, q = lin % 24;
            *(float4*)&Ws[kk][q * 4] = *(const float4*)&Wx[(size_t)(kb + kk) * 96 + q * 4];
        }
        __syncthreads();
        #pragma unroll 8
        for (int kk = 0; kk < 32; ++kk) {
            float a[8];
            *(float4*)&a[0] = *(const float4*)&As[kk][ty * 8];
            *(float4*)&a[4] = *(const float4*)&As[kk][ty * 8 + 4];
            float b0 = Ws[kk][tx], b1 = Ws[kk][tx + 32], b2 = Ws[kk][tx + 64];
            #pragma unroll
            for (int i = 0; i < 8; ++i) {
                acc[i][0] = fmaf(a[i], b0, acc[i][0]);
                acc[i][1] = fmaf(a[i], b1, acc[i][1]);
                acc[i][2] = fmaf(a[i], b2, acc[i][2]);
            }
        }
        __syncthreads();
    }
    float* po = part + (size_t)blockIdx.y * (2 * LSEQ * 96);
    #pragma unroll
    for (int i = 0; i < 8; ++i) {
        int r = row0 + ty * 8 + i;
        po[(size_t)r * 96 + tx]      = acc[i][0];
        po[(size_t)r * 96 + tx + 32] = acc[i][1];
        po[(size_t)r * 96 + tx + 64] = acc[i][2];
    }
}

// Reduce the 8 partials -> xdbl[2048*96].
__global__ __launch_bounds__(256) void xproj_reduce_kernel(
    const float* __restrict__ part, float* __restrict__ xdbl)
{
    const int idx = blockIdx.x * 256 + threadIdx.x;   // [0, 2048*96)
    float s = 0.0f;
    #pragma unroll
    for (int k = 0; k < KSPLIT; ++k)
        s += part[(size_t)k * (2 * LSEQ * 96) + idx];
    xdbl[idx] = s;
}

// ---------------------------------------------------------------------------
// delta = softplus(dt[2048,64] @ W_dt[64,2048] + b_dt). K=64, single stage.
// kk loop unroll CAPPED at 8: full unroll spilled (VGPR=256, 8x write ampl).
// ---------------------------------------------------------------------------
__global__ __launch_bounds__(256) void delta_kernel(
    const float* __restrict__ xdbl, const float* __restrict__ Wdt,
    const float* __restrict__ bdt, float* __restrict__ delta)
{
    __shared__ float As[64][64 + 4];
    __shared__ float Ws[64][64 + 4];
    const int tid  = threadIdx.x;
    const int tx   = tid % 16;
    const int ty   = tid / 16;
    const int row0 = blockIdx.y * 64;
    const int col0 = blockIdx.x * 64;

    #pragma unroll
    for (int i = 0; i < 4; ++i) {
        int lin = tid + i * 256;
        int m = lin / 16, kq = lin % 16;
        float4 v = *(const float4*)&xdbl[(size_t)(row0 + m) * 96 + kq * 4];
        As[kq * 4 + 0][m] = v.x;
        As[kq * 4 + 1][m] = v.y;
        As[kq * 4 + 2][m] = v.z;
        As[kq * 4 + 3][m] = v.w;
    }
    #pragma unroll
    for (int i = 0; i < 4; ++i) {
        int lin = tid + i * 256;
        int kk = lin / 16, q = lin % 16;
        *(float4*)&Ws[kk][q * 4] = *(const float4*)&Wdt[(size_t)kk * DINNER + col0 + q * 4];
    }
    __syncthreads();

    float acc[4][4];
    #pragma unroll
    for (int i = 0; i < 4; ++i)
        #pragma unroll
        for (int j = 0; j < 4; ++j) acc[i][j] = 0.0f;

    #pragma unroll 8
    for (int kk = 0; kk < 64; ++kk) {
        float4 a = *(const float4*)&As[kk][ty * 4];
        float4 b = *(const float4*)&Ws[kk][tx * 4];
        const float* ap = (const float*)&a;
        const float* bp = (const float*)&b;
        #pragma unroll
        for (int i = 0; i < 4; ++i)
            #pragma unroll
            for (int j = 0; j < 4; ++j)
                acc[i][j] = fmaf(ap[i], bp[j], acc[i][j]);
    }

    float4 bv = *(const float4*)&bdt[col0 + tx * 4];
    const float* bvp = (const float*)&bv;
    #pragma unroll
    for (int i = 0; i < 4; ++i) {
        float4 o;
        o.x = softplusf_(acc[i][0] + bvp[0]);
        o.y = softplusf_(acc[i][1] + bvp[1]);
        o.z = softplusf_(acc[i][2] + bvp[2]);
        o.w = softplusf_(acc[i][3] + bvp[3]);
        *(float4*)&delta[(size_t)(row0 + ty * 4 + i) * DINNER + col0 + tx * 4] = o;
    }
}

// ---------------------------------------------------------------------------
// Chunked selective scan — channel-per-thread, N=16 states in registers.
// Thread (b, d, chunk): coalesced delta/xconv/Z along d; B/C via wave-uniform
// (scalarizable) loads; no cross-lane shuffles.
// grid = (DINNER/256, B, NCHUNK), block 256.
// ---------------------------------------------------------------------------
__global__ __launch_bounds__(256) void scan_part1_kernel(
    const float* __restrict__ delta, const float* __restrict__ xconv,
    const float* __restrict__ xdbl, const float* __restrict__ A_log,
    float* __restrict__ Pbuf, float* __restrict__ Hbuf)
{
    const int d  = blockIdx.x * 256 + threadIdx.x;
    const int b  = blockIdx.y;
    const int ch = blockIdx.z;

    float Aa[NSTATE];
    #pragma unroll
    for (int q = 0; q < 4; ++q) {
        float4 v = *(const float4*)&A_log[(size_t)d * NSTATE + q * 4];
        Aa[q * 4 + 0] = -__expf(v.x);
        Aa[q * 4 + 1] = -__expf(v.y);
        Aa[q * 4 + 2] = -__expf(v.z);
        Aa[q * 4 + 3] = -__expf(v.w);
    }
    float h[NSTATE], P[NSTATE];
    #pragma unroll
    for (int n = 0; n < NSTATE; ++n) { h[n] = 0.0f; P[n] = 1.0f; }

    const size_t row0 = (size_t)b * LSEQ + (size_t)ch * CHUNK;
    #pragma unroll 4
    for (int t = 0; t < CHUNK; ++t) {
        const size_t row = row0 + t;
        float dv  = delta[row * DINNER + d];
        float xcv = xconv[row * DINNER + d];
        float du  = dv * xcv;
        const float4* br = (const float4*)&xdbl[row * 96 + RRANK];  // wave-uniform
        float4 B4[4] = { br[0], br[1], br[2], br[3] };
        const float* Bv = (const float*)B4;
        #pragma unroll
        for (int n = 0; n < NSTATE; ++n) {
            float dA = __expf(dv * Aa[n]);
            h[n] = fmaf(dA, h[n], du * Bv[n]);
            P[n] *= dA;
        }
    }
    float* Pp = &Pbuf[(((size_t)ch * 2 + b) * DINNER + d) * NSTATE];
    float* Hp = &Hbuf[(((size_t)ch * 2 + b) * DINNER + d) * NSTATE];
    #pragma unroll
    for (int q = 0; q < 4; ++q) {
        *(float4*)&Pp[q * 4] = *(float4*)&P[q * 4];
        *(float4*)&Hp[q * 4] = *(float4*)&h[q * 4];
    }
}

// Phase 2: per (b,d,n) serial prefix over chunks -> chunk-start states h0.
__global__ __launch_bounds__(256) void scan_combine_kernel(
    const float* __restrict__ Pbuf, const float* __restrict__ Hbuf,
    float* __restrict__ h0buf)
{
    const int idx = blockIdx.x * 256 + threadIdx.x;   // (b*DIN+d)*N+n
    float H = 0.0f;
    #pragma unroll 8
    for (int cch = 0; cch < NCHUNK; ++cch) {
        const size_t g = (size_t)cch * (2 * DINNER * NSTATE) + idx;
        h0buf[g] = H;
        H = fmaf(Pbuf[g], H, Hbuf[g]);
    }
}

// Phase 3: resweep from h0; y = sum_n h[n]*C[n] in-register; +D-skip,
// *silu(z); emit y as bf16 (out_proj consumes bf16).
__global__ __launch_bounds__(256) void scan_part2_kernel(
    const float* __restrict__ delta, const float* __restrict__ xconv,
    const float* __restrict__ xdbl, const float* __restrict__ h0buf,
    const float* __restrict__ Z, u16* __restrict__ yb,
    const float* __restrict__ A_log, const float* __restrict__ Dskip)
{
    const int d  = blockIdx.x * 256 + threadIdx.x;
    const int b  = blockIdx.y;
    const int ch = blockIdx.z;

    float Aa[NSTATE];
    #pragma unroll
    for (int q = 0; q < 4; ++q) {
        float4 v = *(const float4*)&A_log[(size_t)d * NSTATE + q * 4];
        Aa[q * 4 + 0] = -__expf(v.x);
        Aa[q * 4 + 1] = -__expf(v.y);
        Aa[q * 4 + 2] = -__expf(v.z);
        Aa[q * 4 + 3] = -__expf(v.w);
    }
    const float Dd = Dskip[d];

    float h[NSTATE];
    const float* Hp = &h0buf[(((size_t)ch * 2 + b) * DINNER + d) * NSTATE];
    #pragma unroll
    for (int q = 0; q < 4; ++q)
        *(float4*)&h[q * 4] = *(const float4*)&Hp[q * 4];

    const size_t row0 = (size_t)b * LSEQ + (size_t)ch * CHUNK;
    #pragma unroll 2
    for (int t = 0; t < CHUNK; ++t) {
        const size_t row = row0 + t;
        float dv  = delta[row * DINNER + d];
        float xcv = xconv[row * DINNER + d];
        float du  = dv * xcv;
        const float4* br = (const float4*)&xdbl[row * 96 + RRANK];  // wave-uniform
        float4 BC[8] = { br[0], br[1], br[2], br[3], br[4], br[5], br[6], br[7] };
        const float* Bv = (const float*)BC;
        const float* Cv = Bv + NSTATE;
        float y = 0.0f;
        #pragma unroll
        for (int n = 0; n < NSTATE; ++n) {
            float dA = __expf(dv * Aa[n]);
            h[n] = fmaf(dA, h[n], du * Bv[n]);
            y = fmaf(h[n], Cv[n], y);
        }
        float zz = Z[row * DINNER + d];
        float yv = (y + xcv * Dd) * (zz * sigmoidf_(zz));
        yb[row * DINNER + d] = (u16)f2bf(yv);
    }
}

// ---------------------------------------------------------------------------
// Post LayerNorm over D=1024. One block per row.
// ---------------------------------------------------------------------------
__global__ __launch_bounds__(256) void ln_kernel(
    const float* __restrict__ t, const float* __restrict__ g,
    const float* __restrict__ b, float* __restrict__ out)
{
    const int row = blockIdx.x;
    const int tid = threadIdx.x;
    float4 v = *(const float4*)&t[(size_t)row * DMODEL + tid * 4];
    float s = v.x + v.y + v.z + v.w;
    float q = v.x * v.x + v.y * v.y + v.z * v.z + v.w * v.w;
    #pragma unroll
    for (int m = 1; m < 64; m <<= 1) {
        s += __shfl_xor(s, m, 64);
        q += __shfl_xor(q, m, 64);
    }
    __shared__ float ss[4], qq[4];
    if ((tid & 63) == 0) { ss[tid >> 6] = s; qq[tid >> 6] = q; }
    __syncthreads();
    float S = ss[0] + ss[1] + ss[2] + ss[3];
    float Q = qq[0] + qq[1] + qq[2] + qq[3];
    float mu  = S * (1.0f / DMODEL);
    float var = Q * (1.0f / DMODEL) - mu * mu;
    float rs  = rsqrtf(var + 1e-5f);
    float4 gv = *(const float4*)&g[tid * 4];
    float4 bv = *(const float4*)&b[tid * 4];
    float4 o;
    o.x = (v.x - mu) * rs * gv.x + bv.x;
    o.y = (v.y - mu) * rs * gv.y + bv.y;
    o.z = (v.z - mu) * rs * gv.z + bv.z;
    o.w = (v.w - mu) * rs * gv.w + bv.w;
    *(float4*)&out[(size_t)row * DMODEL + tid * 4] = o;
}

// ---------------------------------------------------------------------------
extern "C" void kernel_launch(void* const* d_in, const int* in_sizes, int n_in,
                              void* d_out, int out_size, void* d_ws, size_t ws_size,
                              hipStream_t stream) {
    const float* x      = (const float*)d_in[0];
    const float* W_in   = (const float*)d_in[1];
    const float* conv_w = (const float*)d_in[2];
    const float* conv_b = (const float*)d_in[3];
    const float* W_x    = (const float*)d_in[4];
    const float* W_dt   = (const float*)d_in[5];
    const float* b_dt   = (const float*)d_in[6];
    const float* A_log  = (const float*)d_in[7];
    const float* D_skip = (const float*)d_in[8];
    const float* W_out  = (const float*)d_in[9];
    const float* ln_g   = (const float*)d_in[10];
    const float* ln_b   = (const float*)d_in[11];
    (void)in_sizes; (void)n_in; (void)out_size; (void)ws_size;

    const int M = 2 * LSEQ;  // B*L = 2048

    // Workspace layout (floats). Total = 23,265,280 f = 93,061,120 B.
    float* ws    = (float*)d_ws;
    float* X1    = ws;                               // 4,194,304  x_in (dead after conv)
    float* Z     = X1    + (size_t)M * DINNER;       // 4,194,304  z
    float* xconv = Z     + (size_t)M * DINNER;       // 4,194,304
    float* xdbl  = xconv + (size_t)M * DINNER;       //   196,608
    float* delta = xdbl  + (size_t)M * 96;           // 4,194,304
    float* tmp   = delta + (size_t)M * DINNER;       // 2,097,152  xproj partials -> h0 -> out_proj out
    u16*   xb    = (u16*)(tmp + (size_t)M * DMODEL); // 2,097,152 u16  x bf16
    u16*   Wbin  = xb    + (size_t)M * DMODEL;       // 4,194,304 u16  W_in^T bf16 (dead after in_proj)
    u16*   Wbout = Wbin  + (size_t)2 * DINNER * DMODEL; // 2,097,152 u16  W_out^T bf16
    // Liveness-disjoint aliases:
    u16*   yb    = (u16*)X1;                          // X1[0:8MB)  — y bf16 (X1 dead after conv)
    float* Pbuf  = X1 + (size_t)2 * 1024 * 1024;      // X1[8:16MB) — 2,097,152 f
    float* Hbuf  = (float*)Wbin;                      // Wbin region (dead)  — 2,097,152 f
    float* part  = tmp;                               // 8*2048*96 = 1,572,864 f <= tmp
    float* h0    = tmp;                               // after partials dead

    // 0) casts
    cast_bf16_kernel<<<(M * DMODEL) / (256 * 8), 256, 0, stream>>>(x, xb);
    transpose_cast_kernel<<<dim3((2 * DINNER) / 32, DMODEL / 32), 256, 0, stream>>>(
        W_in, Wbin, DMODEL, 2 * DINNER);
    transpose_cast_kernel<<<dim3(DMODEL / 32, DINNER / 32), 256, 0, stream>>>(
        W_out, Wbout, DINNER, DMODEL);

    // 1) in_proj via bf16 MFMA: X1 = xb @ W_in[:, :2048],  Z = xb @ W_in[:, 2048:]
    mfma_gemm_kernel<128><<<dim3(DINNER / 128, M / 128), 256, 0, stream>>>(
        xb, Wbin, X1, M, DINNER, DMODEL);
    mfma_gemm_kernel<128><<<dim3(DINNER / 128, M / 128), 256, 0, stream>>>(
        xb, Wbin + (size_t)DINNER * DMODEL, Z, M, DINNER, DMODEL);

    // 2) causal depthwise conv + silu   [X1 dead after this]
    conv_silu_kernel<<<(M * (DINNER / 4)) / 256, 256, 0, stream>>>(
        X1, conv_w, conv_b, xconv);

    // 3) x_proj, deterministic split-K
    xproj_part_kernel<<<dim3(M / 64, KSPLIT), 256, 0, stream>>>(xconv, W_x, part);
    xproj_reduce_kernel<<<(M * 96) / 256, 256, 0, stream>>>(part, xdbl);

    // 4) delta = softplus(dt @ W_dt + b_dt)
    delta_kernel<<<dim3(DINNER / 64, M / 64), 256, 0, stream>>>(
        xdbl, W_dt, b_dt, delta);

    // 5) chunked selective scan (channel-per-thread, states in registers)
    scan_part1_kernel<<<dim3(DINNER / 256, 2, NCHUNK), 256, 0, stream>>>(
        delta, xconv, xdbl, A_log, Pbuf, Hbuf);
    scan_combine_kernel<<<(2 * DINNER * NSTATE) / 256, 256, 0, stream>>>(
        Pbuf, Hbuf, h0);
    scan_part2_kernel<<<dim3(DINNER / 256, 2, NCHUNK), 256, 0, stream>>>(
        delta, xconv, xdbl, h0, Z, yb, A_log, D_skip);

    // 6) out_proj via bf16 MFMA: tmp = yb @ W_out   [2048,2048]x[2048,1024]
    mfma_gemm_kernel<64><<<dim3(DMODEL / 64, M / 128), 256, 0, stream>>>(
        yb, Wbout, tmp, M, DMODEL, DINNER);

    // 7) LayerNorm -> d_out
    ln_kernel<<<M, 256, 0, stream>>>(tmp, ln_g, ln_b, (float*)d_out);
}

// Round 6
// 296.391 us; speedup vs baseline: 5.1950x; 1.0905x over previous
//
#include <hip/hip_runtime.h>

// Mamba block fwd: B=2, L=1024, D=1024, DIN=2048, N=16, R=64, K=4
#define LSEQ 1024
#define DMODEL 1024
#define DINNER 2048
#define NSTATE 16
#define RRANK 64
#define CHUNK 32     // timesteps per scan chunk
#define NCHUNK 32    // LSEQ / CHUNK
#define KSPLIT 8     // xproj split-K factor

typedef unsigned short u16;
typedef __attribute__((ext_vector_type(8))) short bf16x8;   // 8 bf16 = 4 VGPRs
typedef __attribute__((ext_vector_type(4))) float f32x4;

__device__ __forceinline__ float sigmoidf_(float x) {
    return 1.0f / (1.0f + __expf(-x));
}
__device__ __forceinline__ float softplusf_(float x) {
    return (x > 20.0f) ? x : log1pf(__expf(x));
}
__device__ __forceinline__ short f2bf(float f) {
    union { float f; unsigned u; } v; v.f = f;
    unsigned r = v.u + 0x7FFF + ((v.u >> 16) & 1);   // RNE
    return (short)(r >> 16);
}

// ---------------------------------------------------------------------------
// fp32 -> bf16 cast, 8 elements/thread.
// ---------------------------------------------------------------------------
__global__ __launch_bounds__(256) void cast_bf16_kernel(
    const float* __restrict__ in, u16* __restrict__ out)
{
    const size_t i = ((size_t)blockIdx.x * 256 + threadIdx.x) * 8;
    float4 a = *(const float4*)&in[i];
    float4 b = *(const float4*)&in[i + 4];
    bf16x8 o;
    o[0] = f2bf(a.x); o[1] = f2bf(a.y); o[2] = f2bf(a.z); o[3] = f2bf(a.w);
    o[4] = f2bf(b.x); o[5] = f2bf(b.y); o[6] = f2bf(b.z); o[7] = f2bf(b.w);
    *(bf16x8*)&out[i] = o;
}

// ---------------------------------------------------------------------------
// Transpose + cast: in[R][C] fp32 -> out[C][R] bf16.  32x32 tiles, 256 thr.
// ---------------------------------------------------------------------------
__global__ __launch_bounds__(256) void transpose_cast_kernel(
    const float* __restrict__ in, u16* __restrict__ out, int R, int C)
{
    __shared__ float t[32][33];
    const int bx = blockIdx.x * 32;   // col base (C dim)
    const int by = blockIdx.y * 32;   // row base (R dim)
    const int tx = threadIdx.x % 32, ty = threadIdx.x / 32;
    #pragma unroll
    for (int i = 0; i < 4; ++i)
        t[ty + 8 * i][tx] = in[(size_t)(by + ty + 8 * i) * C + bx + tx];
    __syncthreads();
    #pragma unroll
    for (int i = 0; i < 4; ++i)
        out[(size_t)(bx + ty + 8 * i) * R + by + tx] = (u16)f2bf(t[tx][ty + 8 * i]);
}

// ---------------------------------------------------------------------------
// bf16 MFMA GEMM: C[M,N] = A[M,K] * Bt[N,K]^T, fp32 out, column-split output:
// cols [0,Nsplit) -> C0 (ldc=Nsplit), cols [Nsplit,N) -> C1 (ldc=N-Nsplit).
// BM x BN block tile, BK=32, 4 waves (2m x 2n), 16x16x32 bf16 MFMA.
// A-frag: [m=lane&15][k=quad*8+j]; B-frag: [n=lane&15][k=quad*8+j];
// C/D: row=quad*4+reg, col=lane&15 (verified layouts, m89/m91/m120).
// Grid sized for >=2 blocks/CU: 1 block/CU exposes the barrier drain (R5 fix).
// ---------------------------------------------------------------------------
template<int BM, int BN>
__global__ __launch_bounds__(256) void mfma_gemm_kernel(
    const u16* __restrict__ A, const u16* __restrict__ Bt,
    float* __restrict__ C0, float* __restrict__ C1,
    int M, int N, int K, int Nsplit)
{
    constexpr int WMS = BM / 32;            // m-subtiles per wave
    constexpr int WNS = BN / 32;            // n-subtiles per wave
    __shared__ u16 lA[BM * 32];
    __shared__ u16 lB[BN * 32];

    const int tid  = threadIdx.x;
    const int lane = tid & 63, wave = tid >> 6;
    const int quad = lane >> 4, l16 = lane & 15;
    const int wm   = (wave >> 1) * (BM / 2);
    const int wn   = (wave & 1) * (BN / 2);
    const int row0 = blockIdx.y * BM;
    const int col0 = blockIdx.x * BN;

    float* Cp; int ccol, ldc;
    if (col0 < Nsplit) { Cp = C0; ccol = col0;          ldc = Nsplit; }
    else               { Cp = C1; ccol = col0 - Nsplit; ldc = N - Nsplit; }

    f32x4 acc[WMS][WNS];
    #pragma unroll
    for (int i = 0; i < WMS; ++i)
        #pragma unroll
        for (int j = 0; j < WNS; ++j)
            acc[i][j] = (f32x4){0.f, 0.f, 0.f, 0.f};

    for (int k0 = 0; k0 < K; k0 += 32) {
        #pragma unroll
        for (int t = 0; t < BM / 64; ++t) {
            int c = tid + t * 256;
            int r = c >> 2, kc = c & 3;
            *(bf16x8*)&lA[r * 32 + kc * 8] =
                *(const bf16x8*)&A[(size_t)(row0 + r) * K + k0 + kc * 8];
        }
        #pragma unroll
        for (int t = 0; t < BN / 64; ++t) {
            int c = tid + t * 256;
            int r = c >> 2, kc = c & 3;
            *(bf16x8*)&lB[r * 32 + kc * 8] =
                *(const bf16x8*)&Bt[(size_t)(col0 + r) * K + k0 + kc * 8];
        }
        __syncthreads();
        bf16x8 af[WMS], bfr[WNS];
        #pragma unroll
        for (int i = 0; i < WMS; ++i)
            af[i] = *(bf16x8*)&lA[(wm + i * 16 + l16) * 32 + quad * 8];
        #pragma unroll
        for (int j = 0; j < WNS; ++j)
            bfr[j] = *(bf16x8*)&lB[(wn + j * 16 + l16) * 32 + quad * 8];
        #pragma unroll
        for (int i = 0; i < WMS; ++i)
            #pragma unroll
            for (int j = 0; j < WNS; ++j)
                acc[i][j] = __builtin_amdgcn_mfma_f32_16x16x32_bf16(
                    af[i], bfr[j], acc[i][j], 0, 0, 0);
        __syncthreads();
    }
    #pragma unroll
    for (int i = 0; i < WMS; ++i)
        #pragma unroll
        for (int j = 0; j < WNS; ++j)
            #pragma unroll
            for (int r = 0; r < 4; ++r)
                Cp[(size_t)(row0 + wm + i * 16 + quad * 4 + r) * ldc
                   + ccol + wn + j * 16 + l16] = acc[i][j][r];
}

// ---------------------------------------------------------------------------
// Causal depthwise conv (K=4) + SiLU.  Reads X1[2048,2048], writes x_conv.
// ---------------------------------------------------------------------------
__global__ __launch_bounds__(256) void conv_silu_kernel(
    const float* __restrict__ X1, const float* __restrict__ cw,
    const float* __restrict__ cb, float* __restrict__ xconv)
{
    const int idx = blockIdx.x * 256 + threadIdx.x;   // over B*L*(DIN/4)
    const int dq  = idx % (DINNER / 4);
    const int bl  = idx / (DINNER / 4);               // b*L + l
    const int l   = bl % LSEQ;
    const int d0  = dq * 4;

    const float4* cw4 = (const float4*)cw;
    const float4 W0 = cw4[d0 + 0];
    const float4 W1 = cw4[d0 + 1];
    const float4 W2 = cw4[d0 + 2];
    const float4 W3 = cw4[d0 + 3];
    float4 s = *(const float4*)&cb[d0];

    #pragma unroll
    for (int k = 0; k < 4; ++k) {
        int ls = l + k - 3;
        if (ls >= 0) {
            float4 xv = *(const float4*)&X1[(size_t)(bl + k - 3) * DINNER + d0];
            s.x = fmaf(xv.x, ((const float*)&W0)[k], s.x);
            s.y = fmaf(xv.y, ((const float*)&W1)[k], s.y);
            s.z = fmaf(xv.z, ((const float*)&W2)[k], s.z);
            s.w = fmaf(xv.w, ((const float*)&W3)[k], s.w);
        }
    }
    s.x *= sigmoidf_(s.x);
    s.y *= sigmoidf_(s.y);
    s.z *= sigmoidf_(s.z);
    s.w *= sigmoidf_(s.w);
    *(float4*)&xconv[(size_t)idx * 4] = s;
}

// ---------------------------------------------------------------------------
// x_proj split-K, deterministic: each k-split writes its own partial.
// ---------------------------------------------------------------------------
__global__ __launch_bounds__(256) void xproj_part_kernel(
    const float* __restrict__ xc, const float* __restrict__ Wx,
    float* __restrict__ part)
{
    __shared__ float As[32][64 + 4];
    __shared__ float Ws[32][96 + 4];

    const int tid  = threadIdx.x;
    const int tx   = tid % 32;
    const int ty   = tid / 32;
    const int row0 = blockIdx.x * 64;
    const int k0   = blockIdx.y * (DINNER / KSPLIT);

    float acc[8][3];
    #pragma unroll
    for (int i = 0; i < 8; ++i) { acc[i][0] = 0.f; acc[i][1] = 0.f; acc[i][2] = 0.f; }

    for (int kt = 0; kt < DINNER / KSPLIT; kt += 32) {
        const int kb = k0 + kt;
        #pragma unroll
        for (int i = 0; i < 2; ++i) {
            int lin = tid + i * 256;
            int m = lin / 8, kq = lin % 8;
            float4 v = *(const float4*)&xc[(size_t)(row0 + m) * DINNER + kb + kq * 4];
            As[kq * 4 + 0][m] = v.x;
            As[kq * 4 + 1][m] = v.y;
            As[kq * 4 + 2][m] = v.z;
            As[kq * 4 + 3][m] = v.w;
        }
        #pragma unroll
        for (int i = 0; i < 3; ++i) {
            int lin = tid + i * 256;
            int kk = lin / 24, q = lin % 24;
            *(float4*)&Ws[kk][q * 4] = *(const float4*)&Wx[(size_t)(kb + kk) * 96 + q * 4];
        }
        __syncthreads();
        #pragma unroll 8
        for (int kk = 0; kk < 32; ++kk) {
            float a[8];
            *(float4*)&a[0] = *(const float4*)&As[kk][ty * 8];
            *(float4*)&a[4] = *(const float4*)&As[kk][ty * 8 + 4];
            float b0 = Ws[kk][tx], b1 = Ws[kk][tx + 32], b2 = Ws[kk][tx + 64];
            #pragma unroll
            for (int i = 0; i < 8; ++i) {
                acc[i][0] = fmaf(a[i], b0, acc[i][0]);
                acc[i][1] = fmaf(a[i], b1, acc[i][1]);
                acc[i][2] = fmaf(a[i], b2, acc[i][2]);
            }
        }
        __syncthreads();
    }
    float* po = part + (size_t)blockIdx.y * (2 * LSEQ * 96);
    #pragma unroll
    for (int i = 0; i < 8; ++i) {
        int r = row0 + ty * 8 + i;
        po[(size_t)r * 96 + tx]      = acc[i][0];
        po[(size_t)r * 96 + tx + 32] = acc[i][1];
        po[(size_t)r * 96 + tx + 64] = acc[i][2];
    }
}

// Reduce the 8 partials -> xdbl[2048*96].
__global__ __launch_bounds__(256) void xproj_reduce_kernel(
    const float* __restrict__ part, float* __restrict__ xdbl)
{
    const int idx = blockIdx.x * 256 + threadIdx.x;   // [0, 2048*96)
    float s = 0.0f;
    #pragma unroll
    for (int k = 0; k < KSPLIT; ++k)
        s += part[(size_t)k * (2 * LSEQ * 96) + idx];
    xdbl[idx] = s;
}

// ---------------------------------------------------------------------------
// delta = softplus(dt[2048,64] @ W_dt[64,2048] + b_dt). K=64, single stage.
// kk loop unroll CAPPED at 8: full unroll spilled (VGPR=256, 8x write ampl).
// ---------------------------------------------------------------------------
__global__ __launch_bounds__(256) void delta_kernel(
    const float* __restrict__ xdbl, const float* __restrict__ Wdt,
    const float* __restrict__ bdt, float* __restrict__ delta)
{
    __shared__ float As[64][64 + 4];
    __shared__ float Ws[64][64 + 4];
    const int tid  = threadIdx.x;
    const int tx   = tid % 16;
    const int ty   = tid / 16;
    const int row0 = blockIdx.y * 64;
    const int col0 = blockIdx.x * 64;

    #pragma unroll
    for (int i = 0; i < 4; ++i) {
        int lin = tid + i * 256;
        int m = lin / 16, kq = lin % 16;
        float4 v = *(const float4*)&xdbl[(size_t)(row0 + m) * 96 + kq * 4];
        As[kq * 4 + 0][m] = v.x;
        As[kq * 4 + 1][m] = v.y;
        As[kq * 4 + 2][m] = v.z;
        As[kq * 4 + 3][m] = v.w;
    }
    #pragma unroll
    for (int i = 0; i < 4; ++i) {
        int lin = tid + i * 256;
        int kk = lin / 16, q = lin % 16;
        *(float4*)&Ws[kk][q * 4] = *(const float4*)&Wdt[(size_t)kk * DINNER + col0 + q * 4];
    }
    __syncthreads();

    float acc[4][4];
    #pragma unroll
    for (int i = 0; i < 4; ++i)
        #pragma unroll
        for (int j = 0; j < 4; ++j) acc[i][j] = 0.0f;

    #pragma unroll 8
    for (int kk = 0; kk < 64; ++kk) {
        float4 a = *(const float4*)&As[kk][ty * 4];
        float4 b = *(const float4*)&Ws[kk][tx * 4];
        const float* ap = (const float*)&a;
        const float* bp = (const float*)&b;
        #pragma unroll
        for (int i = 0; i < 4; ++i)
            #pragma unroll
            for (int j = 0; j < 4; ++j)
                acc[i][j] = fmaf(ap[i], bp[j], acc[i][j]);
    }

    float4 bv = *(const float4*)&bdt[col0 + tx * 4];
    const float* bvp = (const float*)&bv;
    #pragma unroll
    for (int i = 0; i < 4; ++i) {
        float4 o;
        o.x = softplusf_(acc[i][0] + bvp[0]);
        o.y = softplusf_(acc[i][1] + bvp[1]);
        o.z = softplusf_(acc[i][2] + bvp[2]);
        o.w = softplusf_(acc[i][3] + bvp[3]);
        *(float4*)&delta[(size_t)(row0 + ty * 4 + i) * DINNER + col0 + tx * 4] = o;
    }
}

// ---------------------------------------------------------------------------
// Chunked selective scan — channel-per-thread, N=16 states in registers.
// ---------------------------------------------------------------------------
__global__ __launch_bounds__(256) void scan_part1_kernel(
    const float* __restrict__ delta, const float* __restrict__ xconv,
    const float* __restrict__ xdbl, const float* __restrict__ A_log,
    float* __restrict__ Pbuf, float* __restrict__ Hbuf)
{
    const int d  = blockIdx.x * 256 + threadIdx.x;
    const int b  = blockIdx.y;
    const int ch = blockIdx.z;

    float Aa[NSTATE];
    #pragma unroll
    for (int q = 0; q < 4; ++q) {
        float4 v = *(const float4*)&A_log[(size_t)d * NSTATE + q * 4];
        Aa[q * 4 + 0] = -__expf(v.x);
        Aa[q * 4 + 1] = -__expf(v.y);
        Aa[q * 4 + 2] = -__expf(v.z);
        Aa[q * 4 + 3] = -__expf(v.w);
    }
    float h[NSTATE], P[NSTATE];
    #pragma unroll
    for (int n = 0; n < NSTATE; ++n) { h[n] = 0.0f; P[n] = 1.0f; }

    const size_t row0 = (size_t)b * LSEQ + (size_t)ch * CHUNK;
    #pragma unroll 4
    for (int t = 0; t < CHUNK; ++t) {
        const size_t row = row0 + t;
        float dv  = delta[row * DINNER + d];
        float xcv = xconv[row * DINNER + d];
        float du  = dv * xcv;
        const float4* br = (const float4*)&xdbl[row * 96 + RRANK];  // wave-uniform
        float4 B4[4] = { br[0], br[1], br[2], br[3] };
        const float* Bv = (const float*)B4;
        #pragma unroll
        for (int n = 0; n < NSTATE; ++n) {
            float dA = __expf(dv * Aa[n]);
            h[n] = fmaf(dA, h[n], du * Bv[n]);
            P[n] *= dA;
        }
    }
    float* Pp = &Pbuf[(((size_t)ch * 2 + b) * DINNER + d) * NSTATE];
    float* Hp = &Hbuf[(((size_t)ch * 2 + b) * DINNER + d) * NSTATE];
    #pragma unroll
    for (int q = 0; q < 4; ++q) {
        *(float4*)&Pp[q * 4] = *(float4*)&P[q * 4];
        *(float4*)&Hp[q * 4] = *(float4*)&h[q * 4];
    }
}

// Phase 2: per (b,d,n) serial prefix over chunks -> chunk-start states h0.
__global__ __launch_bounds__(256) void scan_combine_kernel(
    const float* __restrict__ Pbuf, const float* __restrict__ Hbuf,
    float* __restrict__ h0buf)
{
    const int idx = blockIdx.x * 256 + threadIdx.x;   // (b*DIN+d)*N+n
    float H = 0.0f;
    #pragma unroll 8
    for (int cch = 0; cch < NCHUNK; ++cch) {
        const size_t g = (size_t)cch * (2 * DINNER * NSTATE) + idx;
        h0buf[g] = H;
        H = fmaf(Pbuf[g], H, Hbuf[g]);
    }
}

// Phase 3: resweep from h0; y = sum_n h[n]*C[n] in-register; +D-skip,
// *silu(z); emit y as bf16 (out_proj consumes bf16).
__global__ __launch_bounds__(256) void scan_part2_kernel(
    const float* __restrict__ delta, const float* __restrict__ xconv,
    const float* __restrict__ xdbl, const float* __restrict__ h0buf,
    const float* __restrict__ Z, u16* __restrict__ yb,
    const float* __restrict__ A_log, const float* __restrict__ Dskip)
{
    const int d  = blockIdx.x * 256 + threadIdx.x;
    const int b  = blockIdx.y;
    const int ch = blockIdx.z;

    float Aa[NSTATE];
    #pragma unroll
    for (int q = 0; q < 4; ++q) {
        float4 v = *(const float4*)&A_log[(size_t)d * NSTATE + q * 4];
        Aa[q * 4 + 0] = -__expf(v.x);
        Aa[q * 4 + 1] = -__expf(v.y);
        Aa[q * 4 + 2] = -__expf(v.z);
        Aa[q * 4 + 3] = -__expf(v.w);
    }
    const float Dd = Dskip[d];

    float h[NSTATE];
    const float* Hp = &h0buf[(((size_t)ch * 2 + b) * DINNER + d) * NSTATE];
    #pragma unroll
    for (int q = 0; q < 4; ++q)
        *(float4*)&h[q * 4] = *(const float4*)&Hp[q * 4];

    const size_t row0 = (size_t)b * LSEQ + (size_t)ch * CHUNK;
    #pragma unroll 2
    for (int t = 0; t < CHUNK; ++t) {
        const size_t row = row0 + t;
        float dv  = delta[row * DINNER + d];
        float xcv = xconv[row * DINNER + d];
        float du  = dv * xcv;
        const float4* br = (const float4*)&xdbl[row * 96 + RRANK];  // wave-uniform
        float4 BC[8] = { br[0], br[1], br[2], br[3], br[4], br[5], br[6], br[7] };
        const float* Bv = (const float*)BC;
        const float* Cv = Bv + NSTATE;
        float y = 0.0f;
        #pragma unroll
        for (int n = 0; n < NSTATE; ++n) {
            float dA = __expf(dv * Aa[n]);
            h[n] = fmaf(dA, h[n], du * Bv[n]);
            y = fmaf(h[n], Cv[n], y);
        }
        float zz = Z[row * DINNER + d];
        float yv = (y + xcv * Dd) * (zz * sigmoidf_(zz));
        yb[row * DINNER + d] = (u16)f2bf(yv);
    }
}

// ---------------------------------------------------------------------------
// Post LayerNorm over D=1024. One block per row.
// ---------------------------------------------------------------------------
__global__ __launch_bounds__(256) void ln_kernel(
    const float* __restrict__ t, const float* __restrict__ g,
    const float* __restrict__ b, float* __restrict__ out)
{
    const int row = blockIdx.x;
    const int tid = threadIdx.x;
    float4 v = *(const float4*)&t[(size_t)row * DMODEL + tid * 4];
    float s = v.x + v.y + v.z + v.w;
    float q = v.x * v.x + v.y * v.y + v.z * v.z + v.w * v.w;
    #pragma unroll
    for (int m = 1; m < 64; m <<= 1) {
        s += __shfl_xor(s, m, 64);
        q += __shfl_xor(q, m, 64);
    }
    __shared__ float ss[4], qq[4];
    if ((tid & 63) == 0) { ss[tid >> 6] = s; qq[tid >> 6] = q; }
    __syncthreads();
    float S = ss[0] + ss[1] + ss[2] + ss[3];
    float Q = qq[0] + qq[1] + qq[2] + qq[3];
    float mu  = S * (1.0f / DMODEL);
    float var = Q * (1.0f / DMODEL) - mu * mu;
    float rs  = rsqrtf(var + 1e-5f);
    float4 gv = *(const float4*)&g[tid * 4];
    float4 bv = *(const float4*)&b[tid * 4];
    float4 o;
    o.x = (v.x - mu) * rs * gv.x + bv.x;
    o.y = (v.y - mu) * rs * gv.y + bv.y;
    o.z = (v.z - mu) * rs * gv.z + bv.z;
    o.w = (v.w - mu) * rs * gv.w + bv.w;
    *(float4*)&out[(size_t)row * DMODEL + tid * 4] = o;
}

// ---------------------------------------------------------------------------
extern "C" void kernel_launch(void* const* d_in, const int* in_sizes, int n_in,
                              void* d_out, int out_size, void* d_ws, size_t ws_size,
                              hipStream_t stream) {
    const float* x      = (const float*)d_in[0];
    const float* W_in   = (const float*)d_in[1];
    const float* conv_w = (const float*)d_in[2];
    const float* conv_b = (const float*)d_in[3];
    const float* W_x    = (const float*)d_in[4];
    const float* W_dt   = (const float*)d_in[5];
    const float* b_dt   = (const float*)d_in[6];
    const float* A_log  = (const float*)d_in[7];
    const float* D_skip = (const float*)d_in[8];
    const float* W_out  = (const float*)d_in[9];
    const float* ln_g   = (const float*)d_in[10];
    const float* ln_b   = (const float*)d_in[11];
    (void)in_sizes; (void)n_in; (void)out_size; (void)ws_size;

    const int M = 2 * LSEQ;  // B*L = 2048

    // Workspace layout (floats). Total = 23,265,280 f = 93,061,120 B.
    float* ws    = (float*)d_ws;
    float* X1    = ws;                               // 4,194,304  x_in (dead after conv)
    float* Z     = X1    + (size_t)M * DINNER;       // 4,194,304  z
    float* xconv = Z     + (size_t)M * DINNER;       // 4,194,304
    float* xdbl  = xconv + (size_t)M * DINNER;       //   196,608
    float* delta = xdbl  + (size_t)M * 96;           // 4,194,304
    float* tmp   = delta + (size_t)M * DINNER;       // 2,097,152  xproj partials -> h0 -> out_proj out
    u16*   xb    = (u16*)(tmp + (size_t)M * DMODEL); // 2,097,152 u16  x bf16
    u16*   Wbin  = xb    + (size_t)M * DMODEL;       // 4,194,304 u16  W_in^T bf16 (dead after in_proj)
    u16*   Wbout = Wbin  + (size_t)2 * DINNER * DMODEL; // 2,097,152 u16  W_out^T bf16
    // Liveness-disjoint aliases:
    u16*   yb    = (u16*)X1;                          // X1[0:8MB)  — y bf16 (X1 dead after conv)
    float* Pbuf  = X1 + (size_t)2 * 1024 * 1024;      // X1[8:16MB) — 2,097,152 f
    float* Hbuf  = (float*)Wbin;                      // Wbin region (dead)  — 2,097,152 f
    float* part  = tmp;                               // 8*2048*96 = 1,572,864 f <= tmp
    float* h0    = tmp;                               // after partials dead

    // 0) casts
    cast_bf16_kernel<<<(M * DMODEL) / (256 * 8), 256, 0, stream>>>(x, xb);
    transpose_cast_kernel<<<dim3((2 * DINNER) / 32, DMODEL / 32), 256, 0, stream>>>(
        W_in, Wbin, DMODEL, 2 * DINNER);
    transpose_cast_kernel<<<dim3(DMODEL / 32, DINNER / 32), 256, 0, stream>>>(
        W_out, Wbout, DINNER, DMODEL);

    // 1) in_proj via bf16 MFMA, ONE dispatch over N=4096 (512 blocks, 2-3/CU):
    //    cols [0,2048) -> X1, cols [2048,4096) -> Z
    mfma_gemm_kernel<128, 128>
        <<<dim3((2 * DINNER) / 128, M / 128), 256, 0, stream>>>(
            xb, Wbin, X1, Z, M, 2 * DINNER, DMODEL, DINNER);

    // 2) causal depthwise conv + silu   [X1 dead after this]
    conv_silu_kernel<<<(M * (DINNER / 4)) / 256, 256, 0, stream>>>(
        X1, conv_w, conv_b, xconv);

    // 3) x_proj, deterministic split-K
    xproj_part_kernel<<<dim3(M / 64, KSPLIT), 256, 0, stream>>>(xconv, W_x, part);
    xproj_reduce_kernel<<<(M * 96) / 256, 256, 0, stream>>>(part, xdbl);

    // 4) delta = softplus(dt @ W_dt + b_dt)
    delta_kernel<<<dim3(DINNER / 64, M / 64), 256, 0, stream>>>(
        xdbl, W_dt, b_dt, delta);

    // 5) chunked selective scan (channel-per-thread, states in registers)
    scan_part1_kernel<<<dim3(DINNER / 256, 2, NCHUNK), 256, 0, stream>>>(
        delta, xconv, xdbl, A_log, Pbuf, Hbuf);
    scan_combine_kernel<<<(2 * DINNER * NSTATE) / 256, 256, 0, stream>>>(
        Pbuf, Hbuf, h0);
    scan_part2_kernel<<<dim3(DINNER / 256, 2, NCHUNK), 256, 0, stream>>>(
        delta, xconv, xdbl, h0, Z, yb, A_log, D_skip);

    // 6) out_proj via bf16 MFMA, 64x64 tiles (512 blocks, 2/CU):
    //    tmp = yb @ W_out   [2048,2048]x[2048,1024]
    mfma_gemm_kernel<64, 64>
        <<<dim3(DMODEL / 64, M / 64), 256, 0, stream>>>(
            yb, Wbout, tmp, tmp, M, DMODEL, DINNER, DMODEL);

    // 7) LayerNorm -> d_out
    ln_kernel<<<M, 256, 0, stream>>>(tmp, ln_g, ln_b, (float*)d_out);
}

// Round 7
// 277.611 us; speedup vs baseline: 5.5465x; 1.0676x over previous
//
#include <hip/hip_runtime.h>

// Mamba block fwd: B=2, L=1024, D=1024, DIN=2048, N=16, R=64, K=4
#define LSEQ 1024
#define DMODEL 1024
#define DINNER 2048
#define NSTATE 16
#define RRANK 64
#define CHUNK 32     // timesteps per scan chunk
#define NCHUNK 32    // LSEQ / CHUNK
#define KSPLIT 8     // xproj split-K factor

typedef unsigned short u16;
typedef __attribute__((ext_vector_type(8))) short bf16x8;   // 8 bf16 = 4 VGPRs
typedef __attribute__((ext_vector_type(4))) short bf16x4;
typedef __attribute__((ext_vector_type(4))) float f32x4;

__device__ __forceinline__ float sigmoidf_(float x) {
    return 1.0f / (1.0f + __expf(-x));
}
__device__ __forceinline__ float softplusf_(float x) {
    return (x > 20.0f) ? x : log1pf(__expf(x));
}
__device__ __forceinline__ short f2bf(float f) {
    union { float f; unsigned u; } v; v.f = f;
    unsigned r = v.u + 0x7FFF + ((v.u >> 16) & 1);   // RNE
    return (short)(r >> 16);
}
__device__ __forceinline__ float bf2f(u16 b) {
    union { unsigned u; float f; } v; v.u = ((unsigned)b) << 16;
    return v.f;
}
// Async global->LDS, 16 B per lane. LDS dest = wave-uniform base + lane*16:
// our staging layouts are lane-contiguous in exactly that order.
__device__ __forceinline__ void async_cp16(const u16* g, u16* l) {
    __builtin_amdgcn_global_load_lds(
        (const __attribute__((address_space(1))) unsigned int*)g,
        (__attribute__((address_space(3))) unsigned int*)l, 16, 0, 0);
}

// ---------------------------------------------------------------------------
// fp32 -> bf16 cast, 8 elements/thread.
// ---------------------------------------------------------------------------
__global__ __launch_bounds__(256) void cast_bf16_kernel(
    const float* __restrict__ in, u16* __restrict__ out)
{
    const size_t i = ((size_t)blockIdx.x * 256 + threadIdx.x) * 8;
    float4 a = *(const float4*)&in[i];
    float4 b = *(const float4*)&in[i + 4];
    bf16x8 o;
    o[0] = f2bf(a.x); o[1] = f2bf(a.y); o[2] = f2bf(a.z); o[3] = f2bf(a.w);
    o[4] = f2bf(b.x); o[5] = f2bf(b.y); o[6] = f2bf(b.z); o[7] = f2bf(b.w);
    *(bf16x8*)&out[i] = o;
}

// ---------------------------------------------------------------------------
// Both weight transposes in ONE dispatch (flattened grid).
// seg0: W_in [1024,4096] -> [4096,1024] bf16   (4096 blocks)
// seg1: W_out [2048,1024] -> [1024,2048] bf16  (2048 blocks)
// ---------------------------------------------------------------------------
__global__ __launch_bounds__(256) void transpose_cast2_kernel(
    const float* __restrict__ in0, u16* __restrict__ out0,
    const float* __restrict__ in1, u16* __restrict__ out1)
{
    __shared__ float t[32][33];
    int bid = blockIdx.x;
    const float* in; u16* out; int R, C, bxi, byi;
    if (bid < 4096) { in = in0; out = out0; R = DMODEL;  C = 2 * DINNER; bxi = bid & 127; byi = bid >> 7; }
    else { bid -= 4096; in = in1; out = out1; R = DINNER; C = DMODEL;    bxi = bid & 31;  byi = bid >> 5; }
    const int bx = bxi * 32, by = byi * 32;
    const int tx = threadIdx.x & 31, ty = threadIdx.x >> 5;
    #pragma unroll
    for (int i = 0; i < 4; ++i)
        t[ty + 8 * i][tx] = in[(size_t)(by + ty + 8 * i) * C + bx + tx];
    __syncthreads();
    #pragma unroll
    for (int i = 0; i < 4; ++i)
        out[(size_t)(bx + ty + 8 * i) * R + by + tx] = (u16)f2bf(t[tx][ty + 8 * i]);
}

// ---------------------------------------------------------------------------
// bf16 MFMA GEMM: C = A[M,K] * Bt[N,K]^T.  Async global_load_lds staging.
// Column-split output: cols [0,Nsplit) -> C0 fp32; if BSPLIT, cols
// [Nsplit,N) -> C1 bf16 (else everything goes to C0, ldc=N).
// BM x BN tile, BK=32, 4 waves (2m x 2n), 16x16x32 bf16 MFMA.
// A/B-frag [mn=lane&15][k=quad*8+j]; C/D row=quad*4+reg, col=lane&15.
// ---------------------------------------------------------------------------
template<int BM, int BN, bool BSPLIT>
__global__ __launch_bounds__(256) void mfma_gemm_kernel(
    const u16* __restrict__ A, const u16* __restrict__ Bt,
    float* __restrict__ C0, u16* __restrict__ C1,
    int M, int N, int K, int Nsplit)
{
    constexpr int WMS = BM / 32;
    constexpr int WNS = BN / 32;
    __shared__ u16 lA[BM * 32];
    __shared__ u16 lB[BN * 32];

    const int tid  = threadIdx.x;
    const int lane = tid & 63, wave = tid >> 6;
    const int quad = lane >> 4, l16 = lane & 15;
    const int wm   = (wave >> 1) * (BM / 2);
    const int wn   = (wave & 1) * (BN / 2);
    const int row0 = blockIdx.y * BM;
    const int col0 = blockIdx.x * BN;

    f32x4 acc[WMS][WNS];
    #pragma unroll
    for (int i = 0; i < WMS; ++i)
        #pragma unroll
        for (int j = 0; j < WNS; ++j)
            acc[i][j] = (f32x4){0.f, 0.f, 0.f, 0.f};

    for (int k0 = 0; k0 < K; k0 += 32) {
        // async stage A tile [BM][32]: lane-contiguous 16B chunks
        #pragma unroll
        for (int t = 0; t < BM / 64; ++t) {
            int c = tid + t * 256;
            int r = c >> 2, kc = c & 3;
            async_cp16(&A[(size_t)(row0 + r) * K + k0 + kc * 8], &lA[c * 8]);
        }
        #pragma unroll
        for (int t = 0; t < BN / 64; ++t) {
            int c = tid + t * 256;
            int r = c >> 2, kc = c & 3;
            async_cp16(&Bt[(size_t)(col0 + r) * K + k0 + kc * 8], &lB[c * 8]);
        }
        __syncthreads();   // compiler drains vmcnt before s_barrier
        bf16x8 af[WMS], bfr[WNS];
        #pragma unroll
        for (int i = 0; i < WMS; ++i)
            af[i] = *(bf16x8*)&lA[(wm + i * 16 + l16) * 32 + quad * 8];
        #pragma unroll
        for (int j = 0; j < WNS; ++j)
            bfr[j] = *(bf16x8*)&lB[(wn + j * 16 + l16) * 32 + quad * 8];
        #pragma unroll
        for (int i = 0; i < WMS; ++i)
            #pragma unroll
            for (int j = 0; j < WNS; ++j)
                acc[i][j] = __builtin_amdgcn_mfma_f32_16x16x32_bf16(
                    af[i], bfr[j], acc[i][j], 0, 0, 0);
        __syncthreads();
    }
    if (!BSPLIT || col0 < Nsplit) {
        const int ldc = BSPLIT ? Nsplit : N;
        #pragma unroll
        for (int i = 0; i < WMS; ++i)
            #pragma unroll
            for (int j = 0; j < WNS; ++j)
                #pragma unroll
                for (int r = 0; r < 4; ++r)
                    C0[(size_t)(row0 + wm + i * 16 + quad * 4 + r) * ldc
                       + col0 + wn + j * 16 + l16] = acc[i][j][r];
    } else {
        const int ldc = N - Nsplit, ccol = col0 - Nsplit;
        #pragma unroll
        for (int i = 0; i < WMS; ++i)
            #pragma unroll
            for (int j = 0; j < WNS; ++j)
                #pragma unroll
                for (int r = 0; r < 4; ++r)
                    C1[(size_t)(row0 + wm + i * 16 + quad * 4 + r) * ldc
                       + ccol + wn + j * 16 + l16] = (u16)f2bf(acc[i][j][r]);
    }
}

// ---------------------------------------------------------------------------
// Causal depthwise conv (K=4) + SiLU.  Reads X1 fp32, writes xconv as bf16.
// ---------------------------------------------------------------------------
__global__ __launch_bounds__(256) void conv_silu_kernel(
    const float* __restrict__ X1, const float* __restrict__ cw,
    const float* __restrict__ cb, u16* __restrict__ xcb)
{
    const int idx = blockIdx.x * 256 + threadIdx.x;   // over B*L*(DIN/4)
    const int dq  = idx % (DINNER / 4);
    const int bl  = idx / (DINNER / 4);               // b*L + l
    const int l   = bl % LSEQ;
    const int d0  = dq * 4;

    const float4* cw4 = (const float4*)cw;
    const float4 W0 = cw4[d0 + 0];
    const float4 W1 = cw4[d0 + 1];
    const float4 W2 = cw4[d0 + 2];
    const float4 W3 = cw4[d0 + 3];
    float4 s = *(const float4*)&cb[d0];

    #pragma unroll
    for (int k = 0; k < 4; ++k) {
        int ls = l + k - 3;
        if (ls >= 0) {
            float4 xv = *(const float4*)&X1[(size_t)(bl + k - 3) * DINNER + d0];
            s.x = fmaf(xv.x, ((const float*)&W0)[k], s.x);
            s.y = fmaf(xv.y, ((const float*)&W1)[k], s.y);
            s.z = fmaf(xv.z, ((const float*)&W2)[k], s.z);
            s.w = fmaf(xv.w, ((const float*)&W3)[k], s.w);
        }
    }
    bf16x4 o;
    o[0] = f2bf(s.x * sigmoidf_(s.x));
    o[1] = f2bf(s.y * sigmoidf_(s.y));
    o[2] = f2bf(s.z * sigmoidf_(s.z));
    o[3] = f2bf(s.w * sigmoidf_(s.w));
    *(bf16x4*)&xcb[(size_t)idx * 4] = o;
}

// ---------------------------------------------------------------------------
// x_proj split-K, deterministic. Reads bf16 xconv (convert during staging).
// ---------------------------------------------------------------------------
__global__ __launch_bounds__(256) void xproj_part_kernel(
    const u16* __restrict__ xcb, const float* __restrict__ Wx,
    float* __restrict__ part)
{
    __shared__ float As[32][64 + 4];
    __shared__ float Ws[32][96 + 4];

    const int tid  = threadIdx.x;
    const int tx   = tid % 32;
    const int ty   = tid / 32;
    const int row0 = blockIdx.x * 64;
    const int k0   = blockIdx.y * (DINNER / KSPLIT);

    float acc[8][3];
    #pragma unroll
    for (int i = 0; i < 8; ++i) { acc[i][0] = 0.f; acc[i][1] = 0.f; acc[i][2] = 0.f; }

    for (int kt = 0; kt < DINNER / KSPLIT; kt += 32) {
        const int kb = k0 + kt;
        {   // 64 rows x 32 ks of bf16: 256 thr x 8 elems
            int m = tid >> 2, kq = tid & 3;
            bf16x8 v = *(const bf16x8*)&xcb[(size_t)(row0 + m) * DINNER + kb + kq * 8];
            #pragma unroll
            for (int j = 0; j < 8; ++j)
                As[kq * 8 + j][m] = bf2f((u16)v[j]);
        }
        #pragma unroll
        for (int i = 0; i < 3; ++i) {
            int lin = tid + i * 256;
            int kk = lin / 24, q = lin % 24;
            *(float4*)&Ws[kk][q * 4] = *(const float4*)&Wx[(size_t)(kb + kk) * 96 + q * 4];
        }
        __syncthreads();
        #pragma unroll 8
        for (int kk = 0; kk < 32; ++kk) {
            float a[8];
            *(float4*)&a[0] = *(const float4*)&As[kk][ty * 8];
            *(float4*)&a[4] = *(const float4*)&As[kk][ty * 8 + 4];
            float b0 = Ws[kk][tx], b1 = Ws[kk][tx + 32], b2 = Ws[kk][tx + 64];
            #pragma unroll
            for (int i = 0; i < 8; ++i) {
                acc[i][0] = fmaf(a[i], b0, acc[i][0]);
                acc[i][1] = fmaf(a[i], b1, acc[i][1]);
                acc[i][2] = fmaf(a[i], b2, acc[i][2]);
            }
        }
        __syncthreads();
    }
    float* po = part + (size_t)blockIdx.y * (2 * LSEQ * 96);
    #pragma unroll
    for (int i = 0; i < 8; ++i) {
        int r = row0 + ty * 8 + i;
        po[(size_t)r * 96 + tx]      = acc[i][0];
        po[(size_t)r * 96 + tx + 32] = acc[i][1];
        po[(size_t)r * 96 + tx + 64] = acc[i][2];
    }
}

// Reduce the 8 partials -> xdbl[2048*96].
__global__ __launch_bounds__(256) void xproj_reduce_kernel(
    const float* __restrict__ part, float* __restrict__ xdbl)
{
    const int idx = blockIdx.x * 256 + threadIdx.x;   // [0, 2048*96)
    float s = 0.0f;
    #pragma unroll
    for (int k = 0; k < KSPLIT; ++k)
        s += part[(size_t)k * (2 * LSEQ * 96) + idx];
    xdbl[idx] = s;
}

// ---------------------------------------------------------------------------
// delta = softplus(dt @ W_dt + b_dt), written as bf16.
// kk loop unroll CAPPED at 8: full unroll spilled (VGPR=256, 8x write ampl).
// ---------------------------------------------------------------------------
__global__ __launch_bounds__(256) void delta_kernel(
    const float* __restrict__ xdbl, const float* __restrict__ Wdt,
    const float* __restrict__ bdt, u16* __restrict__ deltab)
{
    __shared__ float As[64][64 + 4];
    __shared__ float Ws[64][64 + 4];
    const int tid  = threadIdx.x;
    const int tx   = tid % 16;
    const int ty   = tid / 16;
    const int row0 = blockIdx.y * 64;
    const int col0 = blockIdx.x * 64;

    #pragma unroll
    for (int i = 0; i < 4; ++i) {
        int lin = tid + i * 256;
        int m = lin / 16, kq = lin % 16;
        float4 v = *(const float4*)&xdbl[(size_t)(row0 + m) * 96 + kq * 4];
        As[kq * 4 + 0][m] = v.x;
        As[kq * 4 + 1][m] = v.y;
        As[kq * 4 + 2][m] = v.z;
        As[kq * 4 + 3][m] = v.w;
    }
    #pragma unroll
    for (int i = 0; i < 4; ++i) {
        int lin = tid + i * 256;
        int kk = lin / 16, q = lin % 16;
        *(float4*)&Ws[kk][q * 4] = *(const float4*)&Wdt[(size_t)kk * DINNER + col0 + q * 4];
    }
    __syncthreads();

    float acc[4][4];
    #pragma unroll
    for (int i = 0; i < 4; ++i)
        #pragma unroll
        for (int j = 0; j < 4; ++j) acc[i][j] = 0.0f;

    #pragma unroll 8
    for (int kk = 0; kk < 64; ++kk) {
        float4 a = *(const float4*)&As[kk][ty * 4];
        float4 b = *(const float4*)&Ws[kk][tx * 4];
        const float* ap = (const float*)&a;
        const float* bp = (const float*)&b;
        #pragma unroll
        for (int i = 0; i < 4; ++i)
            #pragma unroll
            for (int j = 0; j < 4; ++j)
                acc[i][j] = fmaf(ap[i], bp[j], acc[i][j]);
    }

    float4 bv = *(const float4*)&bdt[col0 + tx * 4];
    const float* bvp = (const float*)&bv;
    #pragma unroll
    for (int i = 0; i < 4; ++i) {
        bf16x4 o;
        o[0] = f2bf(softplusf_(acc[i][0] + bvp[0]));
        o[1] = f2bf(softplusf_(acc[i][1] + bvp[1]));
        o[2] = f2bf(softplusf_(acc[i][2] + bvp[2]));
        o[3] = f2bf(softplusf_(acc[i][3] + bvp[3]));
        *(bf16x4*)&deltab[(size_t)(row0 + ty * 4 + i) * DINNER + col0 + tx * 4] = o;
    }
}

// ---------------------------------------------------------------------------
// Chunked selective scan — channel-per-thread, N=16 states in registers.
// bf16 delta/xconv inputs.
// ---------------------------------------------------------------------------
__global__ __launch_bounds__(256) void scan_part1_kernel(
    const u16* __restrict__ deltab, const u16* __restrict__ xcb,
    const float* __restrict__ xdbl, const float* __restrict__ A_log,
    float* __restrict__ Pbuf, float* __restrict__ Hbuf)
{
    const int d  = blockIdx.x * 256 + threadIdx.x;
    const int b  = blockIdx.y;
    const int ch = blockIdx.z;

    float Aa[NSTATE];
    #pragma unroll
    for (int q = 0; q < 4; ++q) {
        float4 v = *(const float4*)&A_log[(size_t)d * NSTATE + q * 4];
        Aa[q * 4 + 0] = -__expf(v.x);
        Aa[q * 4 + 1] = -__expf(v.y);
        Aa[q * 4 + 2] = -__expf(v.z);
        Aa[q * 4 + 3] = -__expf(v.w);
    }
    float h[NSTATE], P[NSTATE];
    #pragma unroll
    for (int n = 0; n < NSTATE; ++n) { h[n] = 0.0f; P[n] = 1.0f; }

    const size_t row0 = (size_t)b * LSEQ + (size_t)ch * CHUNK;
    #pragma unroll 4
    for (int t = 0; t < CHUNK; ++t) {
        const size_t row = row0 + t;
        float dv  = bf2f(deltab[row * DINNER + d]);
        float xcv = bf2f(xcb[row * DINNER + d]);
        float du  = dv * xcv;
        const float4* br = (const float4*)&xdbl[row * 96 + RRANK];  // wave-uniform
        float4 B4[4] = { br[0], br[1], br[2], br[3] };
        const float* Bv = (const float*)B4;
        #pragma unroll
        for (int n = 0; n < NSTATE; ++n) {
            float dA = __expf(dv * Aa[n]);
            h[n] = fmaf(dA, h[n], du * Bv[n]);
            P[n] *= dA;
        }
    }
    float* Pp = &Pbuf[(((size_t)ch * 2 + b) * DINNER + d) * NSTATE];
    float* Hp = &Hbuf[(((size_t)ch * 2 + b) * DINNER + d) * NSTATE];
    #pragma unroll
    for (int q = 0; q < 4; ++q) {
        *(float4*)&Pp[q * 4] = *(float4*)&P[q * 4];
        *(float4*)&Hp[q * 4] = *(float4*)&h[q * 4];
    }
}

// Phase 2: per (b,d,n) serial prefix over chunks -> chunk-start states h0.
__global__ __launch_bounds__(256) void scan_combine_kernel(
    const float* __restrict__ Pbuf, const float* __restrict__ Hbuf,
    float* __restrict__ h0buf)
{
    const int idx = blockIdx.x * 256 + threadIdx.x;   // (b*DIN+d)*N+n
    float H = 0.0f;
    #pragma unroll 8
    for (int cch = 0; cch < NCHUNK; ++cch) {
        const size_t g = (size_t)cch * (2 * DINNER * NSTATE) + idx;
        h0buf[g] = H;
        H = fmaf(Pbuf[g], H, Hbuf[g]);
    }
}

// Phase 3: resweep from h0; y = sum_n h[n]*C[n]; +D-skip, *silu(z) (bf16 Z);
// emit y as bf16.
__global__ __launch_bounds__(256) void scan_part2_kernel(
    const u16* __restrict__ deltab, const u16* __restrict__ xcb,
    const float* __restrict__ xdbl, const float* __restrict__ h0buf,
    const u16* __restrict__ Zb, u16* __restrict__ yb,
    const float* __restrict__ A_log, const float* __restrict__ Dskip)
{
    const int d  = blockIdx.x * 256 + threadIdx.x;
    const int b  = blockIdx.y;
    const int ch = blockIdx.z;

    float Aa[NSTATE];
    #pragma unroll
    for (int q = 0; q < 4; ++q) {
        float4 v = *(const float4*)&A_log[(size_t)d * NSTATE + q * 4];
        Aa[q * 4 + 0] = -__expf(v.x);
        Aa[q * 4 + 1] = -__expf(v.y);
        Aa[q * 4 + 2] = -__expf(v.z);
        Aa[q * 4 + 3] = -__expf(v.w);
    }
    const float Dd = Dskip[d];

    float h[NSTATE];
    const float* Hp = &h0buf[(((size_t)ch * 2 + b) * DINNER + d) * NSTATE];
    #pragma unroll
    for (int q = 0; q < 4; ++q)
        *(float4*)&h[q * 4] = *(const float4*)&Hp[q * 4];

    const size_t row0 = (size_t)b * LSEQ + (size_t)ch * CHUNK;
    #pragma unroll 2
    for (int t = 0; t < CHUNK; ++t) {
        const size_t row = row0 + t;
        float dv  = bf2f(deltab[row * DINNER + d]);
        float xcv = bf2f(xcb[row * DINNER + d]);
        float du  = dv * xcv;
        const float4* br = (const float4*)&xdbl[row * 96 + RRANK];  // wave-uniform
        float4 BC[8] = { br[0], br[1], br[2], br[3], br[4], br[5], br[6], br[7] };
        const float* Bv = (const float*)BC;
        const float* Cv = Bv + NSTATE;
        float y = 0.0f;
        #pragma unroll
        for (int n = 0; n < NSTATE; ++n) {
            float dA = __expf(dv * Aa[n]);
            h[n] = fmaf(dA, h[n], du * Bv[n]);
            y = fmaf(h[n], Cv[n], y);
        }
        float zz = bf2f(Zb[row * DINNER + d]);
        float yv = (y + xcv * Dd) * (zz * sigmoidf_(zz));
        yb[row * DINNER + d] = (u16)f2bf(yv);
    }
}

// ---------------------------------------------------------------------------
// Post LayerNorm over D=1024. One block per row.
// ---------------------------------------------------------------------------
__global__ __launch_bounds__(256) void ln_kernel(
    const float* __restrict__ t, const float* __restrict__ g,
    const float* __restrict__ b, float* __restrict__ out)
{
    const int row = blockIdx.x;
    const int tid = threadIdx.x;
    float4 v = *(const float4*)&t[(size_t)row * DMODEL + tid * 4];
    float s = v.x + v.y + v.z + v.w;
    float q = v.x * v.x + v.y * v.y + v.z * v.z + v.w * v.w;
    #pragma unroll
    for (int m = 1; m < 64; m <<= 1) {
        s += __shfl_xor(s, m, 64);
        q += __shfl_xor(q, m, 64);
    }
    __shared__ float ss[4], qq[4];
    if ((tid & 63) == 0) { ss[tid >> 6] = s; qq[tid >> 6] = q; }
    __syncthreads();
    float S = ss[0] + ss[1] + ss[2] + ss[3];
    float Q = qq[0] + qq[1] + qq[2] + qq[3];
    float mu  = S * (1.0f / DMODEL);
    float var = Q * (1.0f / DMODEL) - mu * mu;
    float rs  = rsqrtf(var + 1e-5f);
    float4 gv = *(const float4*)&g[tid * 4];
    float4 bv = *(const float4*)&b[tid * 4];
    float4 o;
    o.x = (v.x - mu) * rs * gv.x + bv.x;
    o.y = (v.y - mu) * rs * gv.y + bv.y;
    o.z = (v.z - mu) * rs * gv.z + bv.z;
    o.w = (v.w - mu) * rs * gv.w + bv.w;
    *(float4*)&out[(size_t)row * DMODEL + tid * 4] = o;
}

// ---------------------------------------------------------------------------
extern "C" void kernel_launch(void* const* d_in, const int* in_sizes, int n_in,
                              void* d_out, int out_size, void* d_ws, size_t ws_size,
                              hipStream_t stream) {
    const float* x      = (const float*)d_in[0];
    const float* W_in   = (const float*)d_in[1];
    const float* conv_w = (const float*)d_in[2];
    const float* conv_b = (const float*)d_in[3];
    const float* W_x    = (const float*)d_in[4];
    const float* W_dt   = (const float*)d_in[5];
    const float* b_dt   = (const float*)d_in[6];
    const float* A_log  = (const float*)d_in[7];
    const float* D_skip = (const float*)d_in[8];
    const float* W_out  = (const float*)d_in[9];
    const float* ln_g   = (const float*)d_in[10];
    const float* ln_b   = (const float*)d_in[11];
    (void)in_sizes; (void)n_in; (void)out_size; (void)ws_size;

    const int M = 2 * LSEQ;  // B*L = 2048

    // Workspace layout (floats). Total = 23,265,280 f = 93,061,120 B.
    float* ws    = (float*)d_ws;
    float* X1    = ws;                               // 16 MB slot: x_in fp32 (dead after conv)
    float* Zs    = X1    + (size_t)M * DINNER;       // 16 MB slot: Z bf16 uses low 8 MB
    float* xcs   = Zs    + (size_t)M * DINNER;       // 16 MB slot: xconv bf16 uses low 8 MB
    float* xdbl  = xcs   + (size_t)M * DINNER;       //   196,608 f
    float* dls   = xdbl  + (size_t)M * 96;           // 16 MB slot: delta bf16 uses low 8 MB
    float* tmp   = dls   + (size_t)M * DINNER;       // 8 MB: xproj partials -> h0 -> out_proj out
    u16*   xb    = (u16*)(tmp + (size_t)M * DMODEL); // x bf16 (4 MB)
    u16*   Wbin  = xb    + (size_t)M * DMODEL;       // W_in^T bf16 (8 MB, dead after in_proj)
    u16*   Wbout = Wbin  + (size_t)2 * DINNER * DMODEL; // W_out^T bf16 (4 MB)
    // bf16 views + liveness-disjoint aliases:
    u16*   Zb     = (u16*)Zs;
    u16*   xcb    = (u16*)xcs;
    u16*   deltab = (u16*)dls;
    u16*   yb     = (u16*)X1;                         // X1[0:8MB)  (X1 dead after conv)
    float* Pbuf   = X1 + (size_t)2 * 1024 * 1024;     // X1[8:16MB)
    float* Hbuf   = (float*)Wbin;                     // Wbin region (dead after in_proj)
    float* part   = tmp;                              // 8*2048*96 f <= tmp
    float* h0     = tmp;                              // after partials dead

    // 0) casts (2 dispatches)
    cast_bf16_kernel<<<(M * DMODEL) / (256 * 8), 256, 0, stream>>>(x, xb);
    transpose_cast2_kernel<<<4096 + 2048, 256, 0, stream>>>(W_in, Wbin, W_out, Wbout);

    // 1) in_proj, one dispatch over N=4096: cols [0,2048)->X1 fp32, [2048,4096)->Zb bf16
    mfma_gemm_kernel<128, 128, true>
        <<<dim3((2 * DINNER) / 128, M / 128), 256, 0, stream>>>(
            xb, Wbin, X1, Zb, M, 2 * DINNER, DMODEL, DINNER);

    // 2) causal depthwise conv + silu -> bf16   [X1 dead after this]
    conv_silu_kernel<<<(M * (DINNER / 4)) / 256, 256, 0, stream>>>(
        X1, conv_w, conv_b, xcb);

    // 3) x_proj, deterministic split-K (bf16 input)
    xproj_part_kernel<<<dim3(M / 64, KSPLIT), 256, 0, stream>>>(xcb, W_x, part);
    xproj_reduce_kernel<<<(M * 96) / 256, 256, 0, stream>>>(part, xdbl);

    // 4) delta = softplus(dt @ W_dt + b_dt) -> bf16
    delta_kernel<<<dim3(DINNER / 64, M / 64), 256, 0, stream>>>(
        xdbl, W_dt, b_dt, deltab);

    // 5) chunked selective scan (channel-per-thread, states in registers)
    scan_part1_kernel<<<dim3(DINNER / 256, 2, NCHUNK), 256, 0, stream>>>(
        deltab, xcb, xdbl, A_log, Pbuf, Hbuf);
    scan_combine_kernel<<<(2 * DINNER * NSTATE) / 256, 256, 0, stream>>>(
        Pbuf, Hbuf, h0);
    scan_part2_kernel<<<dim3(DINNER / 256, 2, NCHUNK), 256, 0, stream>>>(
        deltab, xcb, xdbl, h0, Zb, yb, A_log, D_skip);

    // 6) out_proj, 64x64 tiles (512 blocks): tmp = yb @ W_out
    mfma_gemm_kernel<64, 64, false>
        <<<dim3(DMODEL / 64, M / 64), 256, 0, stream>>>(
            yb, Wbout, tmp, (u16*)nullptr, M, DMODEL, DINNER, DMODEL);

    // 7) LayerNorm -> d_out
    ln_kernel<<<M, 256, 0, stream>>>(tmp, ln_g, ln_b, (float*)d_out);
}